// Round 5
// baseline (676.380 us; speedup 1.0000x reference)
//
#include <hip/hip_runtime.h>

typedef unsigned short u16;
typedef __attribute__((ext_vector_type(8))) short short8;
typedef __attribute__((ext_vector_type(4))) short short4v;
typedef __attribute__((ext_vector_type(4))) float floatx4;

#define HD 1024
#define SEQ 4096

__device__ inline u16 f2bf(float f) {
    union { float f; unsigned int i; } c; c.f = f;
    unsigned int r = c.i + 0x7fffu + ((c.i >> 16) & 1u);
    return (u16)(r >> 16);
}

__device__ inline float bf2f(u16 h) {
    union { unsigned int u; float f; } c; c.u = ((unsigned int)h) << 16;
    return c.f;
}

// bijective XCD-chunk swizzle (m204): nwg % 8 == 0 required.
__device__ inline int xcd_chunk(int bid, int nwg) {
    int q = nwg >> 3;
    return (bid & 7) * q + (bid >> 3);
}

// ---------------- Kernel A: x f32 -> bf16 ----------------
__global__ __launch_bounds__(256) void cvt_kernel(const float* __restrict__ in,
                                                  u16* __restrict__ out, int n4) {
    int idx = blockIdx.x * 256 + threadIdx.x;
    int stride = gridDim.x * 256;
    for (int i = idx; i < n4; i += stride) {
        floatx4 v = ((const floatx4*)in)[i];
        short4v o;
        o[0] = (short)f2bf(v[0]); o[1] = (short)f2bf(v[1]);
        o[2] = (short)f2bf(v[2]); o[3] = (short)f2bf(v[3]);
        ((short4v*)out)[i] = o;
    }
}

// ---------------- Kernel 0: W f32 [k][n] -> Wt bf16 [n][k], 3 matrices ----------------
__global__ __launch_bounds__(256) void wt_kernel(const float* __restrict__ Wq,
                                                 const float* __restrict__ Wk,
                                                 const float* __restrict__ Wv,
                                                 u16* __restrict__ wt) {
    __shared__ u16 tile[64 * 65];
    int z = blockIdx.z;
    const float* W = (z == 0) ? Wq : ((z == 1) ? Wk : Wv);
    u16* out = wt + (size_t)z * HD * HD;
    int k0 = blockIdx.x * 64, n0 = blockIdx.y * 64;
    int t = threadIdx.x;
    int r = t >> 4, c4 = (t & 15) * 4;
    for (int h = 0; h < 4; ++h) {
        int row = r + h * 16;
        floatx4 v = *(const floatx4*)(W + (size_t)(k0 + row) * HD + n0 + c4);
        tile[row * 65 + c4 + 0] = f2bf(v[0]);
        tile[row * 65 + c4 + 1] = f2bf(v[1]);
        tile[row * 65 + c4 + 2] = f2bf(v[2]);
        tile[row * 65 + c4 + 3] = f2bf(v[3]);
    }
    __syncthreads();
    int r2 = t >> 3, c8 = (t & 7) * 8;
    union { short8 v; u16 u[8]; } buf;
    for (int h = 0; h < 2; ++h) {
        int rr = r2 + h * 32;
        #pragma unroll
        for (int i = 0; i < 8; ++i) buf.u[i] = tile[(c8 + i) * 65 + rr];
        *(short8*)(out + (size_t)(n0 + rr) * HD + k0 + c8) = buf.v;
    }
}

// ---------------- Kernel 1: QKV GEMM (bf16 in, f32 bias, bf16 out) ----------------
// 128x128 / BK=32 / global_load_lds (validated). LDS ALIASED: sA/sB (16KB,
// K-loop) share the region with tileC (33.8KB, epilogue) — they are never
// live simultaneously (final K-loop barrier separates). 33.8KB total +
// launch_bounds(256,4) -> 4 blocks/CU (was 50KB -> 2.3). VGPR 68 <= 128 cap.
__global__ __launch_bounds__(256, 4) void qkv_gemm(const u16* __restrict__ x,
                                                   const u16* __restrict__ wt,
                                                   const float* __restrict__ bq,
                                                   const float* __restrict__ bk,
                                                   const float* __restrict__ bv,
                                                   u16* __restrict__ qb,
                                                   u16* __restrict__ kbuf,
                                                   u16* __restrict__ vtb) {
    __shared__ __align__(16) char smem[128 * 132 * 2];   // 33792 B
    u16* sA    = (u16*)smem;                             // 8192 B (K-loop)
    u16* sB    = (u16*)(smem + 8192);                    // 8192 B (K-loop)
    u16* tileC = (u16*)smem;                             // 33792 B (epilogue)
    int z = blockIdx.z;
    const u16* Bt = wt + (size_t)z * HD * HD;
    const float* bias = (z == 0) ? bq : ((z == 1) ? bk : bv);
    int m0 = blockIdx.x * 128, n0 = blockIdx.y * 128;
    int t = threadIdx.x, lane = t & 63, w = t >> 6;
    int quad = lane >> 4, l16 = lane & 15;
    int wm = w >> 1, wn = w & 1;
    floatx4 acc[4][4] = {};

    int srow = w * 32 + (lane >> 2);
    int sswz = (lane & 3) ^ ((lane >> 3) & 3);
    const u16* gA = x + (size_t)(m0 + srow) * HD + sswz * 8;
    const u16* gB = Bt + (size_t)(n0 + srow) * HD + sswz * 8;
    u16* lA0 = &sA[(w * 32) * 32];
    u16* lA1 = &sA[(w * 32 + 16) * 32];
    u16* lB0 = &sB[(w * 32) * 32];
    u16* lB1 = &sB[(w * 32 + 16) * 32];

    for (int k0 = 0; k0 < HD; k0 += 32) {
        __builtin_amdgcn_global_load_lds(
            (const __attribute__((address_space(1))) unsigned int*)(const void*)(gA + k0),
            (__attribute__((address_space(3))) unsigned int*)(void*)lA0, 16, 0, 0);
        __builtin_amdgcn_global_load_lds(
            (const __attribute__((address_space(1))) unsigned int*)(const void*)(gA + (size_t)16 * HD + k0),
            (__attribute__((address_space(3))) unsigned int*)(void*)lA1, 16, 0, 0);
        __builtin_amdgcn_global_load_lds(
            (const __attribute__((address_space(1))) unsigned int*)(const void*)(gB + k0),
            (__attribute__((address_space(3))) unsigned int*)(void*)lB0, 16, 0, 0);
        __builtin_amdgcn_global_load_lds(
            (const __attribute__((address_space(1))) unsigned int*)(const void*)(gB + (size_t)16 * HD + k0),
            (__attribute__((address_space(3))) unsigned int*)(void*)lB1, 16, 0, 0);
        __syncthreads();
        short8 af[4], bfr[4];
        #pragma unroll
        for (int i = 0; i < 4; ++i) {
            int ra = wm * 64 + i * 16 + l16;
            af[i] = *(const short8*)&sA[ra * 32 + (quad ^ ((ra >> 1) & 3)) * 8];
        }
        #pragma unroll
        for (int j = 0; j < 4; ++j) {
            int rb = wn * 64 + j * 16 + l16;
            bfr[j] = *(const short8*)&sB[rb * 32 + (quad ^ ((rb >> 1) & 3)) * 8];
        }
        #pragma unroll
        for (int i = 0; i < 4; ++i)
            #pragma unroll
            for (int j = 0; j < 4; ++j)
                acc[i][j] = __builtin_amdgcn_mfma_f32_16x16x32_bf16(af[i], bfr[j], acc[i][j], 0, 0, 0);
        __syncthreads();   // after this, sA/sB dead -> tileC may overwrite
    }

    #pragma unroll
    for (int j = 0; j < 4; ++j) {
        int nl = wn * 64 + j * 16 + l16;
        float bb = bias[n0 + nl];
        #pragma unroll
        for (int i = 0; i < 4; ++i) {
            #pragma unroll
            for (int rr = 0; rr < 4; ++rr) {
                int ml = wm * 64 + i * 16 + quad * 4 + rr;
                tileC[ml * 132 + nl] = f2bf(acc[i][j][rr] + bb);
            }
        }
    }
    __syncthreads();
    int r = t >> 1, c0 = (t & 1) * 64;
    if (z != 2) {
        u16* dst = (z == 0) ? qb : kbuf;
        #pragma unroll
        for (int v = 0; v < 8; ++v) {
            short8 vv = *(const short8*)&tileC[r * 132 + c0 + v * 8];
            *(short8*)&dst[(size_t)(m0 + r) * HD + n0 + c0 + v * 8] = vv;
        }
    } else {
        int b_ = m0 >> 12, s0 = m0 & 4095;
        #pragma unroll
        for (int v = 0; v < 8; ++v) {
            union { short8 vv; u16 u[8]; } pk;
            #pragma unroll
            for (int e = 0; e < 8; ++e) pk.u[e] = tileC[(c0 + v * 8 + e) * 132 + r];
            *(short8*)&vtb[((size_t)(b_ * HD + n0 + r)) * SEQ + s0 + c0 + v * 8] = pk.vv;
        }
    }
}

// ---------------- Kernel S: S = Q K^T / 32  (bf16 out, per batch) ----------------
// Same aliased-LDS + (256,4) occupancy fix. M=N=4096, K=1024 per batch.
__global__ __launch_bounds__(256, 4) void gemm_s(const u16* __restrict__ qb,
                                                 const u16* __restrict__ kb,
                                                 u16* __restrict__ S) {
    __shared__ __align__(16) char smem[128 * 132 * 2];   // 33792 B
    u16* sA    = (u16*)smem;
    u16* sB    = (u16*)(smem + 8192);
    u16* tileC = (u16*)smem;
    int wg = xcd_chunk(blockIdx.x, 4096);
    int b = wg >> 10;
    int r10 = wg & 1023;
    int m0 = (r10 >> 5) * 128, n0 = (r10 & 31) * 128;
    const u16* A = qb + (size_t)b * SEQ * HD;
    const u16* Bt = kb + (size_t)b * SEQ * HD;
    int t = threadIdx.x, lane = t & 63, w = t >> 6;
    int quad = lane >> 4, l16 = lane & 15;
    int wm = w >> 1, wn = w & 1;
    floatx4 acc[4][4] = {};

    int srow = w * 32 + (lane >> 2);
    int sswz = (lane & 3) ^ ((lane >> 3) & 3);
    const u16* gA = A + (size_t)(m0 + srow) * HD + sswz * 8;
    const u16* gB = Bt + (size_t)(n0 + srow) * HD + sswz * 8;
    u16* lA0 = &sA[(w * 32) * 32];
    u16* lA1 = &sA[(w * 32 + 16) * 32];
    u16* lB0 = &sB[(w * 32) * 32];
    u16* lB1 = &sB[(w * 32 + 16) * 32];

    for (int k0 = 0; k0 < HD; k0 += 32) {
        __builtin_amdgcn_global_load_lds(
            (const __attribute__((address_space(1))) unsigned int*)(const void*)(gA + k0),
            (__attribute__((address_space(3))) unsigned int*)(void*)lA0, 16, 0, 0);
        __builtin_amdgcn_global_load_lds(
            (const __attribute__((address_space(1))) unsigned int*)(const void*)(gA + (size_t)16 * HD + k0),
            (__attribute__((address_space(3))) unsigned int*)(void*)lA1, 16, 0, 0);
        __builtin_amdgcn_global_load_lds(
            (const __attribute__((address_space(1))) unsigned int*)(const void*)(gB + k0),
            (__attribute__((address_space(3))) unsigned int*)(void*)lB0, 16, 0, 0);
        __builtin_amdgcn_global_load_lds(
            (const __attribute__((address_space(1))) unsigned int*)(const void*)(gB + (size_t)16 * HD + k0),
            (__attribute__((address_space(3))) unsigned int*)(void*)lB1, 16, 0, 0);
        __syncthreads();
        short8 af[4], bfr[4];
        #pragma unroll
        for (int i = 0; i < 4; ++i) {
            int ra = wm * 64 + i * 16 + l16;
            af[i] = *(const short8*)&sA[ra * 32 + (quad ^ ((ra >> 1) & 3)) * 8];
        }
        #pragma unroll
        for (int j = 0; j < 4; ++j) {
            int rb = wn * 64 + j * 16 + l16;
            bfr[j] = *(const short8*)&sB[rb * 32 + (quad ^ ((rb >> 1) & 3)) * 8];
        }
        #pragma unroll
        for (int i = 0; i < 4; ++i)
            #pragma unroll
            for (int j = 0; j < 4; ++j)
                acc[i][j] = __builtin_amdgcn_mfma_f32_16x16x32_bf16(af[i], bfr[j], acc[i][j], 0, 0, 0);
        __syncthreads();
    }

    #pragma unroll
    for (int j = 0; j < 4; ++j) {
        int nl = wn * 64 + j * 16 + l16;
        #pragma unroll
        for (int i = 0; i < 4; ++i) {
            #pragma unroll
            for (int rr = 0; rr < 4; ++rr) {
                int ml = wm * 64 + i * 16 + quad * 4 + rr;
                tileC[ml * 132 + nl] = f2bf(acc[i][j][rr] * 0.03125f);
            }
        }
    }
    __syncthreads();
    int r = t >> 1, c0 = (t & 1) * 64;
    #pragma unroll
    for (int v = 0; v < 8; ++v) {
        short8 vv = *(const short8*)&tileC[r * 132 + c0 + v * 8];
        *(short8*)&S[((size_t)b * SEQ + m0 + r) * SEQ + n0 + c0 + v * 8] = vv;
    }
}

// ---------------- Kernel SM: in-place row softmax on S (bf16) ----------------
__global__ __launch_bounds__(256) void softmax_kernel(u16* __restrict__ S) {
    int w = threadIdx.x >> 6, lane = threadIdx.x & 63;
    size_t row = (size_t)blockIdx.x * 4 + w;
    u16* p = S + row * SEQ;
    float sv[64];
    float mx = -1e30f;
    #pragma unroll
    for (int c = 0; c < 8; ++c) {
        short8 v = *(const short8*)&p[(c * 64 + lane) * 8];
        #pragma unroll
        for (int e = 0; e < 8; ++e) {
            float f = bf2f((u16)v[e]);
            sv[c * 8 + e] = f;
            mx = fmaxf(mx, f);
        }
    }
    mx = fmaxf(mx, __shfl_xor(mx, 1));
    mx = fmaxf(mx, __shfl_xor(mx, 2));
    mx = fmaxf(mx, __shfl_xor(mx, 4));
    mx = fmaxf(mx, __shfl_xor(mx, 8));
    mx = fmaxf(mx, __shfl_xor(mx, 16));
    mx = fmaxf(mx, __shfl_xor(mx, 32));
    float sum = 0.f;
    #pragma unroll
    for (int i = 0; i < 64; ++i) { sv[i] = __expf(sv[i] - mx); sum += sv[i]; }
    sum += __shfl_xor(sum, 1);
    sum += __shfl_xor(sum, 2);
    sum += __shfl_xor(sum, 4);
    sum += __shfl_xor(sum, 8);
    sum += __shfl_xor(sum, 16);
    sum += __shfl_xor(sum, 32);
    float rinv = 1.f / sum;
    #pragma unroll
    for (int c = 0; c < 8; ++c) {
        union { short8 vv; u16 u[8]; } o;
        #pragma unroll
        for (int e = 0; e < 8; ++e) o.u[e] = f2bf(sv[c * 8 + e] * rinv);
        *(short8*)&p[(c * 64 + lane) * 8] = o.vv;
    }
}

// ---------------- Kernel O: O = P V  (f32 out, per batch) ----------------
// Direct f32 stores (full 64B runs). 16KB LDS + (256,4) -> 4 blocks/CU.
__global__ __launch_bounds__(256, 4) void gemm_o(const u16* __restrict__ P,
                                                 const u16* __restrict__ vt,
                                                 float* __restrict__ out) {
    __shared__ __align__(16) u16 sA[128 * 32];
    __shared__ __align__(16) u16 sB[128 * 32];
    int wg = xcd_chunk(blockIdx.x, 1024);
    int b = wg >> 8;
    int r8 = wg & 255;
    int m0 = (r8 >> 3) * 128, n0 = (r8 & 7) * 128;
    const u16* A = P + (size_t)b * SEQ * SEQ;
    const u16* Bt = vt + (size_t)b * HD * SEQ;
    int t = threadIdx.x, lane = t & 63, w = t >> 6;
    int quad = lane >> 4, l16 = lane & 15;
    int wm = w >> 1, wn = w & 1;
    floatx4 acc[4][4] = {};

    int srow = w * 32 + (lane >> 2);
    int sswz = (lane & 3) ^ ((lane >> 3) & 3);
    const u16* gA = A + (size_t)(m0 + srow) * SEQ + sswz * 8;
    const u16* gB = Bt + (size_t)(n0 + srow) * SEQ + sswz * 8;
    u16* lA0 = &sA[(w * 32) * 32];
    u16* lA1 = &sA[(w * 32 + 16) * 32];
    u16* lB0 = &sB[(w * 32) * 32];
    u16* lB1 = &sB[(w * 32 + 16) * 32];

    for (int k0 = 0; k0 < SEQ; k0 += 32) {
        __builtin_amdgcn_global_load_lds(
            (const __attribute__((address_space(1))) unsigned int*)(const void*)(gA + k0),
            (__attribute__((address_space(3))) unsigned int*)(void*)lA0, 16, 0, 0);
        __builtin_amdgcn_global_load_lds(
            (const __attribute__((address_space(1))) unsigned int*)(const void*)(gA + (size_t)16 * SEQ + k0),
            (__attribute__((address_space(3))) unsigned int*)(void*)lA1, 16, 0, 0);
        __builtin_amdgcn_global_load_lds(
            (const __attribute__((address_space(1))) unsigned int*)(const void*)(gB + k0),
            (__attribute__((address_space(3))) unsigned int*)(void*)lB0, 16, 0, 0);
        __builtin_amdgcn_global_load_lds(
            (const __attribute__((address_space(1))) unsigned int*)(const void*)(gB + (size_t)16 * SEQ + k0),
            (__attribute__((address_space(3))) unsigned int*)(void*)lB1, 16, 0, 0);
        __syncthreads();
        short8 af[4], bfr[4];
        #pragma unroll
        for (int i = 0; i < 4; ++i) {
            int ra = wm * 64 + i * 16 + l16;
            af[i] = *(const short8*)&sA[ra * 32 + (quad ^ ((ra >> 1) & 3)) * 8];
        }
        #pragma unroll
        for (int j = 0; j < 4; ++j) {
            int rb = wn * 64 + j * 16 + l16;
            bfr[j] = *(const short8*)&sB[rb * 32 + (quad ^ ((rb >> 1) & 3)) * 8];
        }
        #pragma unroll
        for (int i = 0; i < 4; ++i)
            #pragma unroll
            for (int j = 0; j < 4; ++j)
                acc[i][j] = __builtin_amdgcn_mfma_f32_16x16x32_bf16(af[i], bfr[j], acc[i][j], 0, 0, 0);
        __syncthreads();
    }

    #pragma unroll
    for (int j = 0; j < 4; ++j) {
        int n = n0 + wn * 64 + j * 16 + l16;
        #pragma unroll
        for (int i = 0; i < 4; ++i) {
            #pragma unroll
            for (int rr = 0; rr < 4; ++rr) {
                int m = m0 + wm * 64 + i * 16 + quad * 4 + rr;
                out[((size_t)(b * SEQ + m)) * HD + n] = acc[i][j][rr];
            }
        }
    }
}

// ---------------- Fallback: flash attention (proven, 590us) ----------------
__global__ __launch_bounds__(512, 2) void flash_kernel(const u16* __restrict__ q,
                                                       const u16* __restrict__ k,
                                                       const u16* __restrict__ vt,
                                                       float* __restrict__ out) {
    __shared__ __align__(16) u16 q_lds[64 * 1032];
    __shared__ float Sc[64 * 66];
    __shared__ __align__(16) u16 Pb[64 * 72];
    __shared__ float m_st[64], l_st[64], al_st[64];

    int t = threadIdx.x, lane = t & 63, w = t >> 6;
    int quad = lane >> 4, l16 = lane & 15;
    int j = w & 3, hh = w >> 2;
    int bid = blockIdx.x;
    int xcd = bid & 7;
    int b = xcd >> 1;
    int q0 = (((bid >> 3) << 1) + (xcd & 1)) * 64;

    for (int i = t; i < 64 * 128; i += 512) {
        int r = i >> 7, c8 = (i & 127) * 8;
        *(short8*)&q_lds[r * 1032 + c8] =
            *(const short8*)&q[((size_t)(b * SEQ + q0 + r)) * HD + c8];
    }
    if (t < 64) { m_st[t] = -1e30f; l_st[t] = 0.f; }
    floatx4 o_acc[4][8] = {};
    __syncthreads();

    const u16* kwave = k + ((size_t)(b * SEQ + j * 16 + l16)) * HD + hh * 512 + quad * 8;
    const u16* vwave = vt + ((size_t)(b * HD + w * 128 + l16)) * SEQ + quad * 8;
    int r2 = t >> 3;
    int cg = (t & 7) * 8;

    for (int tt = 0; tt < 64; ++tt) {
        int kb = tt * 64;
        floatx4 s_acc[4] = {};
        const u16* kp = kwave + (size_t)kb * HD;
        #pragma unroll 8
        for (int ks = 0; ks < 16; ++ks) {
            short8 kf = *(const short8*)(kp + ks * 32);
            #pragma unroll
            for (int rb = 0; rb < 4; ++rb) {
                short8 qf = *(const short8*)&q_lds[(rb * 16 + l16) * 1032 + hh * 512 + ks * 32 + quad * 8];
                s_acc[rb] = __builtin_amdgcn_mfma_f32_16x16x32_bf16(qf, kf, s_acc[rb], 0, 0, 0);
            }
        }
        if (hh == 0) {
            #pragma unroll
            for (int rb = 0; rb < 4; ++rb)
                #pragma unroll
                for (int rr = 0; rr < 4; ++rr)
                    Sc[(rb * 16 + quad * 4 + rr) * 66 + j * 16 + l16] = s_acc[rb][rr] * 0.03125f;
        }
        __syncthreads();
        if (hh == 1) {
            #pragma unroll
            for (int rb = 0; rb < 4; ++rb)
                #pragma unroll
                for (int rr = 0; rr < 4; ++rr)
                    Sc[(rb * 16 + quad * 4 + rr) * 66 + j * 16 + l16] += s_acc[rb][rr] * 0.03125f;
        }
        __syncthreads();

        float sv[8];
        float mloc = -1e30f;
        #pragma unroll
        for (int i = 0; i < 8; ++i) { sv[i] = Sc[r2 * 66 + cg + i]; mloc = fmaxf(mloc, sv[i]); }
        mloc = fmaxf(mloc, __shfl_xor(mloc, 1));
        mloc = fmaxf(mloc, __shfl_xor(mloc, 2));
        mloc = fmaxf(mloc, __shfl_xor(mloc, 4));
        float m_old = m_st[r2];
        float m_new = fmaxf(m_old, mloc);
        float alpha = __expf(m_old - m_new);
        float sum = 0.f;
        #pragma unroll
        for (int i = 0; i < 8; ++i) {
            float p = __expf(sv[i] - m_new);
            sum += p;
            Pb[r2 * 72 + cg + i] = f2bf(p);
        }
        sum += __shfl_xor(sum, 1);
        sum += __shfl_xor(sum, 2);
        sum += __shfl_xor(sum, 4);
        if ((t & 7) == 0) {
            m_st[r2] = m_new;
            l_st[r2] = l_st[r2] * alpha + sum;
            al_st[r2] = alpha;
        }
        __syncthreads();

        #pragma unroll
        for (int rb = 0; rb < 4; ++rb) {
            float a0 = al_st[rb * 16 + quad * 4 + 0];
            float a1 = al_st[rb * 16 + quad * 4 + 1];
            float a2 = al_st[rb * 16 + quad * 4 + 2];
            float a3 = al_st[rb * 16 + quad * 4 + 3];
            #pragma unroll
            for (int dt = 0; dt < 8; ++dt) {
                o_acc[rb][dt][0] *= a0;
                o_acc[rb][dt][1] *= a1;
                o_acc[rb][dt][2] *= a2;
                o_acc[rb][dt][3] *= a3;
            }
        }
        short8 pf[4][2];
        #pragma unroll
        for (int rb = 0; rb < 4; ++rb)
            #pragma unroll
            for (int ks2 = 0; ks2 < 2; ++ks2)
                pf[rb][ks2] = *(const short8*)&Pb[(rb * 16 + l16) * 72 + ks2 * 32 + quad * 8];
        const u16* vp = vwave + kb;
        #pragma unroll
        for (int dt = 0; dt < 8; ++dt) {
            short8 vf0 = *(const short8*)(vp + (size_t)dt * 16 * SEQ);
            short8 vf1 = *(const short8*)(vp + (size_t)dt * 16 * SEQ + 32);
            #pragma unroll
            for (int rb = 0; rb < 4; ++rb) {
                o_acc[rb][dt] = __builtin_amdgcn_mfma_f32_16x16x32_bf16(pf[rb][0], vf0, o_acc[rb][dt], 0, 0, 0);
                o_acc[rb][dt] = __builtin_amdgcn_mfma_f32_16x16x32_bf16(pf[rb][1], vf1, o_acc[rb][dt], 0, 0, 0);
            }
        }
    }

    #pragma unroll
    for (int rb = 0; rb < 4; ++rb) {
        #pragma unroll
        for (int rr = 0; rr < 4; ++rr) {
            int row = rb * 16 + quad * 4 + rr;
            float linv = 1.f / l_st[row];
            #pragma unroll
            for (int dt = 0; dt < 8; ++dt) {
                out[((size_t)(b * SEQ + q0 + row)) * HD + w * 128 + dt * 16 + l16] =
                    o_acc[rb][dt][rr] * linv;
            }
        }
    }
}

extern "C" void kernel_launch(void* const* d_in, const int* in_sizes, int n_in,
                              void* d_out, int out_size, void* d_ws, size_t ws_size,
                              hipStream_t stream) {
    const float* x  = (const float*)d_in[0];
    const float* Wq = (const float*)d_in[1];
    const float* bq = (const float*)d_in[2];
    const float* Wk = (const float*)d_in[3];
    const float* bk = (const float*)d_in[4];
    const float* Wv = (const float*)d_in[5];
    const float* bv = (const float*)d_in[6];
    float* out = (float*)d_out;
    char* ws = (char*)d_ws;
    const size_t MB = 1024 * 1024;

    if (ws_size >= 224 * MB) {
        // Unfused path. Layout (peak 224 MB):
        //   vtb @0 (32MB) | qb @32 (32MB) | kb @64 (32MB) | S @96..224 (128MB)
        //   xb @96 (32MB, dead before S written) | wt @128 (6MB, dead too)
        u16* vtb = (u16*)ws;
        u16* qb  = (u16*)(ws + 32 * MB);
        u16* kb  = (u16*)(ws + 64 * MB);
        u16* S   = (u16*)(ws + 96 * MB);
        u16* xb  = (u16*)(ws + 96 * MB);
        u16* wt  = (u16*)(ws + 128 * MB);

        cvt_kernel<<<dim3(4096), 256, 0, stream>>>(x, xb, (4 * SEQ * HD) / 4);
        wt_kernel<<<dim3(16, 16, 3), 256, 0, stream>>>(Wq, Wk, Wv, wt);
        qkv_gemm<<<dim3(128, 8, 3), 256, 0, stream>>>(xb, wt, bq, bk, bv, qb, kb, vtb);
        gemm_s<<<dim3(4096), 256, 0, stream>>>(qb, kb, S);
        softmax_kernel<<<dim3(4096), 256, 0, stream>>>(S);
        gemm_o<<<dim3(1024), 256, 0, stream>>>(S, vtb, out);
    } else {
        // Fallback: proven flash path (134 MB).
        u16* xb  = (u16*)ws;
        u16* wt  = (u16*)(ws + 32 * MB);
        u16* qb  = (u16*)(ws + 38 * MB);
        u16* kb  = (u16*)(ws + 70 * MB);
        u16* vtb = (u16*)(ws + 102 * MB);

        cvt_kernel<<<dim3(4096), 256, 0, stream>>>(x, xb, (4 * SEQ * HD) / 4);
        wt_kernel<<<dim3(16, 16, 3), 256, 0, stream>>>(Wq, Wk, Wv, wt);
        qkv_gemm<<<dim3(128, 8, 3), 256, 0, stream>>>(xb, wt, bq, bk, bv, qb, kb, vtb);
        flash_kernel<<<dim3(256), 512, 0, stream>>>(qb, kb, vtb, out);
    }
}

// Round 6
// 568.374 us; speedup vs baseline: 1.1900x; 1.1900x over previous
//
#include <hip/hip_runtime.h>

typedef unsigned short u16;
typedef __attribute__((ext_vector_type(8))) short short8;
typedef __attribute__((ext_vector_type(4))) short short4v;
typedef __attribute__((ext_vector_type(4))) float floatx4;

#define HD 1024
#define SEQ 4096

__device__ inline u16 f2bf(float f) {
    union { float f; unsigned int i; } c; c.f = f;
    unsigned int r = c.i + 0x7fffu + ((c.i >> 16) & 1u);
    return (u16)(r >> 16);
}

__device__ inline float bf2f(u16 h) {
    union { unsigned int u; float f; } c; c.u = ((unsigned int)h) << 16;
    return c.f;
}

// bijective XCD-chunk swizzle (m204): nwg % 8 == 0 required.
__device__ inline int xcd_chunk(int bid, int nwg) {
    int q = nwg >> 3;
    return (bid & 7) * q + (bid >> 3);
}

// ---------------- Kernel A: x f32 -> bf16 ----------------
__global__ __launch_bounds__(256) void cvt_kernel(const float* __restrict__ in,
                                                  u16* __restrict__ out, int n4) {
    int idx = blockIdx.x * 256 + threadIdx.x;
    int stride = gridDim.x * 256;
    for (int i = idx; i < n4; i += stride) {
        floatx4 v = ((const floatx4*)in)[i];
        short4v o;
        o[0] = (short)f2bf(v[0]); o[1] = (short)f2bf(v[1]);
        o[2] = (short)f2bf(v[2]); o[3] = (short)f2bf(v[3]);
        ((short4v*)out)[i] = o;
    }
}

// ---------------- Kernel 0: W f32 [k][n] -> Wt bf16 [n][k], 3 matrices ----------------
__global__ __launch_bounds__(256) void wt_kernel(const float* __restrict__ Wq,
                                                 const float* __restrict__ Wk,
                                                 const float* __restrict__ Wv,
                                                 u16* __restrict__ wt) {
    __shared__ u16 tile[64 * 65];
    int z = blockIdx.z;
    const float* W = (z == 0) ? Wq : ((z == 1) ? Wk : Wv);
    u16* out = wt + (size_t)z * HD * HD;
    int k0 = blockIdx.x * 64, n0 = blockIdx.y * 64;
    int t = threadIdx.x;
    int r = t >> 4, c4 = (t & 15) * 4;
    for (int h = 0; h < 4; ++h) {
        int row = r + h * 16;
        floatx4 v = *(const floatx4*)(W + (size_t)(k0 + row) * HD + n0 + c4);
        tile[row * 65 + c4 + 0] = f2bf(v[0]);
        tile[row * 65 + c4 + 1] = f2bf(v[1]);
        tile[row * 65 + c4 + 2] = f2bf(v[2]);
        tile[row * 65 + c4 + 3] = f2bf(v[3]);
    }
    __syncthreads();
    int r2 = t >> 3, c8 = (t & 7) * 8;
    union { short8 v; u16 u[8]; } buf;
    for (int h = 0; h < 2; ++h) {
        int rr = r2 + h * 32;
        #pragma unroll
        for (int i = 0; i < 8; ++i) buf.u[i] = tile[(c8 + i) * 65 + rr];
        *(short8*)(out + (size_t)(n0 + rr) * HD + k0 + c8) = buf.v;
    }
}

// ---------------- Kernel 1: QKV GEMM (round-4 exact: (256,2), 50KB LDS) ----------------
__global__ __launch_bounds__(256, 2) void qkv_gemm(const u16* __restrict__ x,
                                                   const u16* __restrict__ wt,
                                                   const float* __restrict__ bq,
                                                   const float* __restrict__ bk,
                                                   const float* __restrict__ bv,
                                                   u16* __restrict__ qb,
                                                   u16* __restrict__ kbuf,
                                                   u16* __restrict__ vtb) {
    __shared__ __align__(16) u16 sA[128 * 32];
    __shared__ __align__(16) u16 sB[128 * 32];
    __shared__ __align__(16) u16 tileC[128 * 132];
    int z = blockIdx.z;
    const u16* Bt = wt + (size_t)z * HD * HD;
    const float* bias = (z == 0) ? bq : ((z == 1) ? bk : bv);
    int m0 = blockIdx.x * 128, n0 = blockIdx.y * 128;
    int t = threadIdx.x, lane = t & 63, w = t >> 6;
    int quad = lane >> 4, l16 = lane & 15;
    int wm = w >> 1, wn = w & 1;
    floatx4 acc[4][4] = {};

    int srow = w * 32 + (lane >> 2);
    int sswz = (lane & 3) ^ ((lane >> 3) & 3);
    const u16* gA = x + (size_t)(m0 + srow) * HD + sswz * 8;
    const u16* gB = Bt + (size_t)(n0 + srow) * HD + sswz * 8;
    u16* lA0 = &sA[(w * 32) * 32];
    u16* lA1 = &sA[(w * 32 + 16) * 32];
    u16* lB0 = &sB[(w * 32) * 32];
    u16* lB1 = &sB[(w * 32 + 16) * 32];

    for (int k0 = 0; k0 < HD; k0 += 32) {
        __builtin_amdgcn_global_load_lds(
            (const __attribute__((address_space(1))) unsigned int*)(const void*)(gA + k0),
            (__attribute__((address_space(3))) unsigned int*)(void*)lA0, 16, 0, 0);
        __builtin_amdgcn_global_load_lds(
            (const __attribute__((address_space(1))) unsigned int*)(const void*)(gA + (size_t)16 * HD + k0),
            (__attribute__((address_space(3))) unsigned int*)(void*)lA1, 16, 0, 0);
        __builtin_amdgcn_global_load_lds(
            (const __attribute__((address_space(1))) unsigned int*)(const void*)(gB + k0),
            (__attribute__((address_space(3))) unsigned int*)(void*)lB0, 16, 0, 0);
        __builtin_amdgcn_global_load_lds(
            (const __attribute__((address_space(1))) unsigned int*)(const void*)(gB + (size_t)16 * HD + k0),
            (__attribute__((address_space(3))) unsigned int*)(void*)lB1, 16, 0, 0);
        __syncthreads();
        short8 af[4], bfr[4];
        #pragma unroll
        for (int i = 0; i < 4; ++i) {
            int ra = wm * 64 + i * 16 + l16;
            af[i] = *(const short8*)&sA[ra * 32 + (quad ^ ((ra >> 1) & 3)) * 8];
        }
        #pragma unroll
        for (int j = 0; j < 4; ++j) {
            int rb = wn * 64 + j * 16 + l16;
            bfr[j] = *(const short8*)&sB[rb * 32 + (quad ^ ((rb >> 1) & 3)) * 8];
        }
        #pragma unroll
        for (int i = 0; i < 4; ++i)
            #pragma unroll
            for (int j = 0; j < 4; ++j)
                acc[i][j] = __builtin_amdgcn_mfma_f32_16x16x32_bf16(af[i], bfr[j], acc[i][j], 0, 0, 0);
        __syncthreads();
    }

    #pragma unroll
    for (int j = 0; j < 4; ++j) {
        int nl = wn * 64 + j * 16 + l16;
        float bb = bias[n0 + nl];
        #pragma unroll
        for (int i = 0; i < 4; ++i) {
            #pragma unroll
            for (int rr = 0; rr < 4; ++rr) {
                int ml = wm * 64 + i * 16 + quad * 4 + rr;
                tileC[ml * 132 + nl] = f2bf(acc[i][j][rr] + bb);
            }
        }
    }
    __syncthreads();
    int r = t >> 1, c0 = (t & 1) * 64;
    if (z != 2) {
        u16* dst = (z == 0) ? qb : kbuf;
        #pragma unroll
        for (int v = 0; v < 8; ++v) {
            short8 vv = *(const short8*)&tileC[r * 132 + c0 + v * 8];
            *(short8*)&dst[(size_t)(m0 + r) * HD + n0 + c0 + v * 8] = vv;
        }
    } else {
        int b_ = m0 >> 12, s0 = m0 & 4095;
        #pragma unroll
        for (int v = 0; v < 8; ++v) {
            union { short8 vv; u16 u[8]; } pk;
            #pragma unroll
            for (int e = 0; e < 8; ++e) pk.u[e] = tileC[(c0 + v * 8 + e) * 132 + r];
            *(short8*)&vtb[((size_t)(b_ * HD + n0 + r)) * SEQ + s0 + c0 + v * 8] = pk.vv;
        }
    }
}

// ---------------- gemm256: 256x256 tile, counted-vmcnt pipelined GEMM ----------------
// C[b][m][n] = scale * sum_k A[b][m][k] * B[b][n][k]   (B given row-major over n, i.e. B^T)
// 8 waves (512 thr), per-wave 128x64 output, BK=32, 4-slot LDS ring (128 KB),
// prefetch depth 3 K-tiles via global_load_lds; per K-tile:
//   s_waitcnt vmcnt(8)  [own oldest tile landed]  ->  s_barrier  [all waves' loads published]
//   stage(kt+3)  [into slot whose reads finished at kt-1 -- safe post-barrier]
//   ds_read frags (verified swizzle layout) -> 32 MFMA (setprio-wrapped)
// NEVER vmcnt(0) in steady state; 1 barrier/K-tile (vs 2 + full drain in m97 structure).
template<int LDA, int LDB, int LDC, int KT, int MT, int NT, bool F32OUT>
__global__ __launch_bounds__(512, 2) void gemm256(const u16* __restrict__ A,
                                                  const u16* __restrict__ B,
                                                  void* __restrict__ C,
                                                  float scale) {
    __shared__ __align__(16) u16 ring[4][2][256 * 32];   // 128 KiB
    constexpr int NWG = 4 * MT * NT;
    int wg = xcd_chunk(blockIdx.x, NWG);
    int b = wg / (MT * NT);
    int r = wg % (MT * NT);
    int m0 = (r / NT) * 256, n0 = (r % NT) * 256;
    const u16* Ab = A + (size_t)b * MT * 256 * LDA;
    const u16* Bb = B + (size_t)b * NT * 256 * LDB;

    int t = threadIdx.x, lane = t & 63, w = t >> 6;
    int quad = lane >> 4, l16 = lane & 15;
    int wm = w >> 2, wn = w & 3;

    // staging: wave w owns rows [w*32, w*32+32) of both A and B tiles.
    // dest linear (gload_lds: base + lane*16B); source col-slot pre-swizzled
    // so that LDS[r][s] = global[r][s ^ ((r>>1)&3)] (verified layout).
    int srow = w * 32 + (lane >> 2);
    int sswz = (lane & 3) ^ ((lane >> 3) & 3);
    const u16* gAs = Ab + (size_t)(m0 + srow) * LDA + sswz * 8;
    const u16* gBs = Bb + (size_t)(n0 + srow) * LDB + sswz * 8;

    auto stage = [&](int kt_) {
        int s_ = kt_ & 3;
        const u16* a0 = gAs + (size_t)kt_ * 32;
        const u16* b0 = gBs + (size_t)kt_ * 32;
        u16* dA = &ring[s_][0][(w * 32) * 32];
        u16* dB = &ring[s_][1][(w * 32) * 32];
        __builtin_amdgcn_global_load_lds(
            (const __attribute__((address_space(1))) unsigned int*)(const void*)a0,
            (__attribute__((address_space(3))) unsigned int*)(void*)dA, 16, 0, 0);
        __builtin_amdgcn_global_load_lds(
            (const __attribute__((address_space(1))) unsigned int*)(const void*)(a0 + (size_t)16 * LDA),
            (__attribute__((address_space(3))) unsigned int*)(void*)(dA + 16 * 32), 16, 0, 0);
        __builtin_amdgcn_global_load_lds(
            (const __attribute__((address_space(1))) unsigned int*)(const void*)b0,
            (__attribute__((address_space(3))) unsigned int*)(void*)dB, 16, 0, 0);
        __builtin_amdgcn_global_load_lds(
            (const __attribute__((address_space(1))) unsigned int*)(const void*)(b0 + (size_t)16 * LDB),
            (__attribute__((address_space(3))) unsigned int*)(void*)(dB + 16 * 32), 16, 0, 0);
    };

    stage(0); stage(1); stage(2);   // 12 loads/thread in flight

    floatx4 acc[8][4] = {};

    for (int kt = 0; kt < KT; ++kt) {
        // own loads for kt landed (4 per K-tile; keep later tiles in flight)
        if (kt + 2 < KT)       asm volatile("s_waitcnt vmcnt(8)" ::: "memory");
        else if (kt + 2 == KT) asm volatile("s_waitcnt vmcnt(4)" ::: "memory");
        else                   asm volatile("s_waitcnt vmcnt(0)" ::: "memory");
        __builtin_amdgcn_s_barrier();      // publishes ALL waves' kt loads
        asm volatile("" ::: "memory");     // no LDS op may hoist above barrier
        if (kt + 3 < KT) stage(kt + 3);    // slot (kt-1)&3: reads done pre-barrier

        const u16* As = &ring[kt & 3][0][0];
        const u16* Bs = &ring[kt & 3][1][0];
        short8 bf[4], af[8];
        #pragma unroll
        for (int j = 0; j < 4; ++j) {
            int rb = wn * 64 + j * 16 + l16;
            bf[j] = *(const short8*)&Bs[rb * 32 + (quad ^ ((rb >> 1) & 3)) * 8];
        }
        #pragma unroll
        for (int i = 0; i < 8; ++i) {
            int ra = wm * 128 + i * 16 + l16;
            af[i] = *(const short8*)&As[ra * 32 + (quad ^ ((ra >> 1) & 3)) * 8];
        }
        __builtin_amdgcn_s_setprio(1);
        #pragma unroll
        for (int i = 0; i < 8; ++i)
            #pragma unroll
            for (int j = 0; j < 4; ++j)
                acc[i][j] = __builtin_amdgcn_mfma_f32_16x16x32_bf16(af[i], bf[j], acc[i][j], 0, 0, 0);
        __builtin_amdgcn_s_setprio(0);
    }

    if constexpr (F32OUT) {
        float* Cb = (float*)C + (size_t)b * MT * 256 * LDC;
        #pragma unroll
        for (int i = 0; i < 8; ++i)
            #pragma unroll
            for (int rr = 0; rr < 4; ++rr) {
                int m = m0 + wm * 128 + i * 16 + quad * 4 + rr;
                float* row = Cb + (size_t)m * LDC + n0 + wn * 64 + l16;
                #pragma unroll
                for (int j = 0; j < 4; ++j)
                    row[j * 16] = acc[i][j][rr] * scale;
            }
    } else {
        u16* Cb = (u16*)C + (size_t)b * MT * 256 * LDC;
        #pragma unroll
        for (int i = 0; i < 8; ++i)
            #pragma unroll
            for (int rr = 0; rr < 4; ++rr) {
                int m = m0 + wm * 128 + i * 16 + quad * 4 + rr;
                u16* row = Cb + (size_t)m * LDC + n0 + wn * 64 + l16;
                #pragma unroll
                for (int j = 0; j < 4; ++j)
                    row[j * 16] = f2bf(acc[i][j][rr] * scale);
            }
    }
}

// ---------------- Kernel SM: in-place row softmax on S (bf16) ----------------
__global__ __launch_bounds__(256) void softmax_kernel(u16* __restrict__ S) {
    int w = threadIdx.x >> 6, lane = threadIdx.x & 63;
    size_t row = (size_t)blockIdx.x * 4 + w;
    u16* p = S + row * SEQ;
    float sv[64];
    float mx = -1e30f;
    #pragma unroll
    for (int c = 0; c < 8; ++c) {
        short8 v = *(const short8*)&p[(c * 64 + lane) * 8];
        #pragma unroll
        for (int e = 0; e < 8; ++e) {
            float f = bf2f((u16)v[e]);
            sv[c * 8 + e] = f;
            mx = fmaxf(mx, f);
        }
    }
    mx = fmaxf(mx, __shfl_xor(mx, 1));
    mx = fmaxf(mx, __shfl_xor(mx, 2));
    mx = fmaxf(mx, __shfl_xor(mx, 4));
    mx = fmaxf(mx, __shfl_xor(mx, 8));
    mx = fmaxf(mx, __shfl_xor(mx, 16));
    mx = fmaxf(mx, __shfl_xor(mx, 32));
    float sum = 0.f;
    #pragma unroll
    for (int i = 0; i < 64; ++i) { sv[i] = __expf(sv[i] - mx); sum += sv[i]; }
    sum += __shfl_xor(sum, 1);
    sum += __shfl_xor(sum, 2);
    sum += __shfl_xor(sum, 4);
    sum += __shfl_xor(sum, 8);
    sum += __shfl_xor(sum, 16);
    sum += __shfl_xor(sum, 32);
    float rinv = 1.f / sum;
    #pragma unroll
    for (int c = 0; c < 8; ++c) {
        union { short8 vv; u16 u[8]; } o;
        #pragma unroll
        for (int e = 0; e < 8; ++e) o.u[e] = f2bf(sv[c * 8 + e] * rinv);
        *(short8*)&p[(c * 64 + lane) * 8] = o.vv;
    }
}

// ---------------- Fallback: flash attention (proven, 590us) ----------------
__global__ __launch_bounds__(512, 2) void flash_kernel(const u16* __restrict__ q,
                                                       const u16* __restrict__ k,
                                                       const u16* __restrict__ vt,
                                                       float* __restrict__ out) {
    __shared__ __align__(16) u16 q_lds[64 * 1032];
    __shared__ float Sc[64 * 66];
    __shared__ __align__(16) u16 Pb[64 * 72];
    __shared__ float m_st[64], l_st[64], al_st[64];

    int t = threadIdx.x, lane = t & 63, w = t >> 6;
    int quad = lane >> 4, l16 = lane & 15;
    int j = w & 3, hh = w >> 2;
    int bid = blockIdx.x;
    int xcd = bid & 7;
    int b = xcd >> 1;
    int q0 = (((bid >> 3) << 1) + (xcd & 1)) * 64;

    for (int i = t; i < 64 * 128; i += 512) {
        int r = i >> 7, c8 = (i & 127) * 8;
        *(short8*)&q_lds[r * 1032 + c8] =
            *(const short8*)&q[((size_t)(b * SEQ + q0 + r)) * HD + c8];
    }
    if (t < 64) { m_st[t] = -1e30f; l_st[t] = 0.f; }
    floatx4 o_acc[4][8] = {};
    __syncthreads();

    const u16* kwave = k + ((size_t)(b * SEQ + j * 16 + l16)) * HD + hh * 512 + quad * 8;
    const u16* vwave = vt + ((size_t)(b * HD + w * 128 + l16)) * SEQ + quad * 8;
    int r2 = t >> 3;
    int cg = (t & 7) * 8;

    for (int tt = 0; tt < 64; ++tt) {
        int kb = tt * 64;
        floatx4 s_acc[4] = {};
        const u16* kp = kwave + (size_t)kb * HD;
        #pragma unroll 8
        for (int ks = 0; ks < 16; ++ks) {
            short8 kf = *(const short8*)(kp + ks * 32);
            #pragma unroll
            for (int rb = 0; rb < 4; ++rb) {
                short8 qf = *(const short8*)&q_lds[(rb * 16 + l16) * 1032 + hh * 512 + ks * 32 + quad * 8];
                s_acc[rb] = __builtin_amdgcn_mfma_f32_16x16x32_bf16(qf, kf, s_acc[rb], 0, 0, 0);
            }
        }
        if (hh == 0) {
            #pragma unroll
            for (int rb = 0; rb < 4; ++rb)
                #pragma unroll
                for (int rr = 0; rr < 4; ++rr)
                    Sc[(rb * 16 + quad * 4 + rr) * 66 + j * 16 + l16] = s_acc[rb][rr] * 0.03125f;
        }
        __syncthreads();
        if (hh == 1) {
            #pragma unroll
            for (int rb = 0; rb < 4; ++rb)
                #pragma unroll
                for (int rr = 0; rr < 4; ++rr)
                    Sc[(rb * 16 + quad * 4 + rr) * 66 + j * 16 + l16] += s_acc[rb][rr] * 0.03125f;
        }
        __syncthreads();

        float sv[8];
        float mloc = -1e30f;
        #pragma unroll
        for (int i = 0; i < 8; ++i) { sv[i] = Sc[r2 * 66 + cg + i]; mloc = fmaxf(mloc, sv[i]); }
        mloc = fmaxf(mloc, __shfl_xor(mloc, 1));
        mloc = fmaxf(mloc, __shfl_xor(mloc, 2));
        mloc = fmaxf(mloc, __shfl_xor(mloc, 4));
        float m_old = m_st[r2];
        float m_new = fmaxf(m_old, mloc);
        float alpha = __expf(m_old - m_new);
        float sum = 0.f;
        #pragma unroll
        for (int i = 0; i < 8; ++i) {
            float p = __expf(sv[i] - m_new);
            sum += p;
            Pb[r2 * 72 + cg + i] = f2bf(p);
        }
        sum += __shfl_xor(sum, 1);
        sum += __shfl_xor(sum, 2);
        sum += __shfl_xor(sum, 4);
        if ((t & 7) == 0) {
            m_st[r2] = m_new;
            l_st[r2] = l_st[r2] * alpha + sum;
            al_st[r2] = alpha;
        }
        __syncthreads();

        #pragma unroll
        for (int rb = 0; rb < 4; ++rb) {
            float a0 = al_st[rb * 16 + quad * 4 + 0];
            float a1 = al_st[rb * 16 + quad * 4 + 1];
            float a2 = al_st[rb * 16 + quad * 4 + 2];
            float a3 = al_st[rb * 16 + quad * 4 + 3];
            #pragma unroll
            for (int dt = 0; dt < 8; ++dt) {
                o_acc[rb][dt][0] *= a0;
                o_acc[rb][dt][1] *= a1;
                o_acc[rb][dt][2] *= a2;
                o_acc[rb][dt][3] *= a3;
            }
        }
        short8 pf[4][2];
        #pragma unroll
        for (int rb = 0; rb < 4; ++rb)
            #pragma unroll
            for (int ks2 = 0; ks2 < 2; ++ks2)
                pf[rb][ks2] = *(const short8*)&Pb[(rb * 16 + l16) * 72 + ks2 * 32 + quad * 8];
        const u16* vp = vwave + kb;
        #pragma unroll
        for (int dt = 0; dt < 8; ++dt) {
            short8 vf0 = *(const short8*)(vp + (size_t)dt * 16 * SEQ);
            short8 vf1 = *(const short8*)(vp + (size_t)dt * 16 * SEQ + 32);
            #pragma unroll
            for (int rb = 0; rb < 4; ++rb) {
                o_acc[rb][dt] = __builtin_amdgcn_mfma_f32_16x16x32_bf16(pf[rb][0], vf0, o_acc[rb][dt], 0, 0, 0);
                o_acc[rb][dt] = __builtin_amdgcn_mfma_f32_16x16x32_bf16(pf[rb][1], vf1, o_acc[rb][dt], 0, 0, 0);
            }
        }
    }

    #pragma unroll
    for (int rb = 0; rb < 4; ++rb) {
        #pragma unroll
        for (int rr = 0; rr < 4; ++rr) {
            int row = rb * 16 + quad * 4 + rr;
            float linv = 1.f / l_st[row];
            #pragma unroll
            for (int dt = 0; dt < 8; ++dt) {
                out[((size_t)(b * SEQ + q0 + row)) * HD + w * 128 + dt * 16 + l16] =
                    o_acc[rb][dt][rr] * linv;
            }
        }
    }
}

extern "C" void kernel_launch(void* const* d_in, const int* in_sizes, int n_in,
                              void* d_out, int out_size, void* d_ws, size_t ws_size,
                              hipStream_t stream) {
    const float* x  = (const float*)d_in[0];
    const float* Wq = (const float*)d_in[1];
    const float* bq = (const float*)d_in[2];
    const float* Wk = (const float*)d_in[3];
    const float* bk = (const float*)d_in[4];
    const float* Wv = (const float*)d_in[5];
    const float* bv = (const float*)d_in[6];
    float* out = (float*)d_out;
    char* ws = (char*)d_ws;
    const size_t MB = 1024 * 1024;

    if (ws_size >= 224 * MB) {
        // Unfused path. Layout (peak 224 MB):
        //   vtb @0 (32MB) | qb @32 (32MB) | kb @64 (32MB) | S @96..224 (128MB)
        //   xb @96 (32MB, dead before S written) | wt @128 (6MB, dead too)
        u16* vtb = (u16*)ws;
        u16* qb  = (u16*)(ws + 32 * MB);
        u16* kb  = (u16*)(ws + 64 * MB);
        u16* S   = (u16*)(ws + 96 * MB);
        u16* xb  = (u16*)(ws + 96 * MB);
        u16* wt  = (u16*)(ws + 128 * MB);

        cvt_kernel<<<dim3(4096), 256, 0, stream>>>(x, xb, (4 * SEQ * HD) / 4);
        wt_kernel<<<dim3(16, 16, 3), 256, 0, stream>>>(Wq, Wk, Wv, wt);
        qkv_gemm<<<dim3(128, 8, 3), 256, 0, stream>>>(xb, wt, bq, bk, bv, qb, kb, vtb);
        // S = Q K^T / 32 : M=N=4096, K=1024 per batch, bf16 out
        gemm256<HD, HD, SEQ, 32, 16, 16, false><<<dim3(1024), 512, 0, stream>>>(qb, kb, S, 0.03125f);
        softmax_kernel<<<dim3(4096), 256, 0, stream>>>(S);
        // O = P V : M=4096, N=1024, K=4096 per batch, f32 out (B = vt rows over d)
        gemm256<SEQ, SEQ, HD, 128, 16, 4, true><<<dim3(256), 512, 0, stream>>>(S, vtb, out, 1.0f);
    } else {
        // Fallback: proven flash path (134 MB).
        u16* xb  = (u16*)ws;
        u16* wt  = (u16*)(ws + 32 * MB);
        u16* qb  = (u16*)(ws + 38 * MB);
        u16* kb  = (u16*)(ws + 70 * MB);
        u16* vtb = (u16*)(ws + 102 * MB);

        cvt_kernel<<<dim3(4096), 256, 0, stream>>>(x, xb, (4 * SEQ * HD) / 4);
        wt_kernel<<<dim3(16, 16, 3), 256, 0, stream>>>(Wq, Wk, Wv, wt);
        qkv_gemm<<<dim3(128, 8, 3), 256, 0, stream>>>(xb, wt, bq, bk, bv, qb, kb, vtb);
        flash_kernel<<<dim3(256), 512, 0, stream>>>(qb, kb, vtb, out);
    }
}

// Round 7
// 548.438 us; speedup vs baseline: 1.2333x; 1.0364x over previous
//
#include <hip/hip_runtime.h>

typedef unsigned short u16;
typedef __attribute__((ext_vector_type(8))) short short8;
typedef __attribute__((ext_vector_type(4))) short short4v;
typedef __attribute__((ext_vector_type(4))) float floatx4;

#define HD 1024
#define SEQ 4096

__device__ inline u16 f2bf(float f) {
    union { float f; unsigned int i; } c; c.f = f;
    unsigned int r = c.i + 0x7fffu + ((c.i >> 16) & 1u);
    return (u16)(r >> 16);
}

__device__ inline float bf2f(u16 h) {
    union { unsigned int u; float f; } c; c.u = ((unsigned int)h) << 16;
    return c.f;
}

// bijective XCD-chunk swizzle (m204): nwg % 8 == 0 required.
__device__ inline int xcd_chunk(int bid, int nwg) {
    int q = nwg >> 3;
    return (bid & 7) * q + (bid >> 3);
}

// ---------------- Kernel A: x f32 -> bf16 ----------------
__global__ __launch_bounds__(256) void cvt_kernel(const float* __restrict__ in,
                                                  u16* __restrict__ out, int n4) {
    int idx = blockIdx.x * 256 + threadIdx.x;
    int stride = gridDim.x * 256;
    for (int i = idx; i < n4; i += stride) {
        floatx4 v = ((const floatx4*)in)[i];
        short4v o;
        o[0] = (short)f2bf(v[0]); o[1] = (short)f2bf(v[1]);
        o[2] = (short)f2bf(v[2]); o[3] = (short)f2bf(v[3]);
        ((short4v*)out)[i] = o;
    }
}

// ---------------- Kernel 0: W f32 [k][n] -> Wt bf16 [n][k], 3 matrices ----------------
__global__ __launch_bounds__(256) void wt_kernel(const float* __restrict__ Wq,
                                                 const float* __restrict__ Wk,
                                                 const float* __restrict__ Wv,
                                                 u16* __restrict__ wt) {
    __shared__ u16 tile[64 * 65];
    int z = blockIdx.z;
    const float* W = (z == 0) ? Wq : ((z == 1) ? Wk : Wv);
    u16* out = wt + (size_t)z * HD * HD;
    int k0 = blockIdx.x * 64, n0 = blockIdx.y * 64;
    int t = threadIdx.x;
    int r = t >> 4, c4 = (t & 15) * 4;
    for (int h = 0; h < 4; ++h) {
        int row = r + h * 16;
        floatx4 v = *(const floatx4*)(W + (size_t)(k0 + row) * HD + n0 + c4);
        tile[row * 65 + c4 + 0] = f2bf(v[0]);
        tile[row * 65 + c4 + 1] = f2bf(v[1]);
        tile[row * 65 + c4 + 2] = f2bf(v[2]);
        tile[row * 65 + c4 + 3] = f2bf(v[3]);
    }
    __syncthreads();
    int r2 = t >> 3, c8 = (t & 7) * 8;
    union { short8 v; u16 u[8]; } buf;
    for (int h = 0; h < 2; ++h) {
        int rr = r2 + h * 32;
        #pragma unroll
        for (int i = 0; i < 8; ++i) buf.u[i] = tile[(c8 + i) * 65 + rr];
        *(short8*)(out + (size_t)(n0 + rr) * HD + k0 + c8) = buf.v;
    }
}

// ---------------- qkv256: Q,K projections via the counted-vmcnt 256^2 structure ----------------
// 512 wgs = 64 m-tiles x 4 n-tiles x 2 (z: 0=Q 1=K). Bias fused. Row-major bf16 out.
// Exact gemm256 pipeline: 4-slot ring, depth-3 prefetch, vmcnt(8) steady state.
__global__ __launch_bounds__(512, 2) void qkv256(const u16* __restrict__ x,
                                                 const u16* __restrict__ wt,
                                                 const float* __restrict__ bq,
                                                 const float* __restrict__ bk,
                                                 u16* __restrict__ qb,
                                                 u16* __restrict__ kbuf) {
    __shared__ __align__(16) u16 ring[4][2][256 * 32];   // 128 KiB
    int wg = xcd_chunk(blockIdx.x, 512);
    int z = wg >> 8;
    int r = wg & 255;
    int m0 = (r >> 2) * 256, n0 = (r & 3) * 256;
    const u16* Bb = wt + (size_t)z * HD * HD;
    const float* bias = z ? bk : bq;
    u16* C = z ? kbuf : qb;

    int t = threadIdx.x, lane = t & 63, w = t >> 6;
    int quad = lane >> 4, l16 = lane & 15;
    int wm = w >> 2, wn = w & 3;

    int srow = w * 32 + (lane >> 2);
    int sswz = (lane & 3) ^ ((lane >> 3) & 3);
    const u16* gAs = x + (size_t)(m0 + srow) * HD + sswz * 8;
    const u16* gBs = Bb + (size_t)(n0 + srow) * HD + sswz * 8;

    auto stage = [&](int kt_) {
        int s_ = kt_ & 3;
        const u16* a0 = gAs + (size_t)kt_ * 32;
        const u16* b0 = gBs + (size_t)kt_ * 32;
        u16* dA = &ring[s_][0][(w * 32) * 32];
        u16* dB = &ring[s_][1][(w * 32) * 32];
        __builtin_amdgcn_global_load_lds(
            (const __attribute__((address_space(1))) unsigned int*)(const void*)a0,
            (__attribute__((address_space(3))) unsigned int*)(void*)dA, 16, 0, 0);
        __builtin_amdgcn_global_load_lds(
            (const __attribute__((address_space(1))) unsigned int*)(const void*)(a0 + (size_t)16 * HD),
            (__attribute__((address_space(3))) unsigned int*)(void*)(dA + 16 * 32), 16, 0, 0);
        __builtin_amdgcn_global_load_lds(
            (const __attribute__((address_space(1))) unsigned int*)(const void*)b0,
            (__attribute__((address_space(3))) unsigned int*)(void*)dB, 16, 0, 0);
        __builtin_amdgcn_global_load_lds(
            (const __attribute__((address_space(1))) unsigned int*)(const void*)(b0 + (size_t)16 * HD),
            (__attribute__((address_space(3))) unsigned int*)(void*)(dB + 16 * 32), 16, 0, 0);
    };

    stage(0); stage(1); stage(2);

    floatx4 acc[8][4] = {};
    constexpr int KT = HD / 32;

    for (int kt = 0; kt < KT; ++kt) {
        if (kt + 2 < KT)       asm volatile("s_waitcnt vmcnt(8)" ::: "memory");
        else if (kt + 2 == KT) asm volatile("s_waitcnt vmcnt(4)" ::: "memory");
        else                   asm volatile("s_waitcnt vmcnt(0)" ::: "memory");
        __builtin_amdgcn_s_barrier();
        asm volatile("" ::: "memory");
        if (kt + 3 < KT) stage(kt + 3);

        const u16* As = &ring[kt & 3][0][0];
        const u16* Bs = &ring[kt & 3][1][0];
        short8 bf[4], af[8];
        #pragma unroll
        for (int j = 0; j < 4; ++j) {
            int rb = wn * 64 + j * 16 + l16;
            bf[j] = *(const short8*)&Bs[rb * 32 + (quad ^ ((rb >> 1) & 3)) * 8];
        }
        #pragma unroll
        for (int i = 0; i < 8; ++i) {
            int ra = wm * 128 + i * 16 + l16;
            af[i] = *(const short8*)&As[ra * 32 + (quad ^ ((ra >> 1) & 3)) * 8];
        }
        __builtin_amdgcn_s_setprio(1);
        #pragma unroll
        for (int i = 0; i < 8; ++i)
            #pragma unroll
            for (int j = 0; j < 4; ++j)
                acc[i][j] = __builtin_amdgcn_mfma_f32_16x16x32_bf16(af[i], bf[j], acc[i][j], 0, 0, 0);
        __builtin_amdgcn_s_setprio(0);
    }

    float bb[4];
    #pragma unroll
    for (int j = 0; j < 4; ++j) bb[j] = bias[n0 + wn * 64 + j * 16 + l16];
    #pragma unroll
    for (int i = 0; i < 8; ++i)
        #pragma unroll
        for (int rr = 0; rr < 4; ++rr) {
            int m = m0 + wm * 128 + i * 16 + quad * 4 + rr;
            u16* row = C + (size_t)m * HD + n0 + wn * 64 + l16;
            #pragma unroll
            for (int j = 0; j < 4; ++j)
                row[j * 16] = f2bf(acc[i][j][rr] + bb[j]);
        }
}

// ---------------- v_gemm: V projection (old validated 128^2 structure, z==2 only) ----------------
// B = wtv, bias bv, output vtb transposed [b][d][s] via tileC bounce.
__global__ __launch_bounds__(256, 2) void v_gemm(const u16* __restrict__ x,
                                                 const u16* __restrict__ wtv,
                                                 const float* __restrict__ bv,
                                                 u16* __restrict__ vtb) {
    __shared__ __align__(16) u16 sA[128 * 32];
    __shared__ __align__(16) u16 sB[128 * 32];
    __shared__ __align__(16) u16 tileC[128 * 132];
    int m0 = blockIdx.x * 128, n0 = blockIdx.y * 128;
    int t = threadIdx.x, lane = t & 63, w = t >> 6;
    int quad = lane >> 4, l16 = lane & 15;
    int wm = w >> 1, wn = w & 1;
    floatx4 acc[4][4] = {};

    int srow = w * 32 + (lane >> 2);
    int sswz = (lane & 3) ^ ((lane >> 3) & 3);
    const u16* gA = x + (size_t)(m0 + srow) * HD + sswz * 8;
    const u16* gB = wtv + (size_t)(n0 + srow) * HD + sswz * 8;
    u16* lA0 = &sA[(w * 32) * 32];
    u16* lA1 = &sA[(w * 32 + 16) * 32];
    u16* lB0 = &sB[(w * 32) * 32];
    u16* lB1 = &sB[(w * 32 + 16) * 32];

    for (int k0 = 0; k0 < HD; k0 += 32) {
        __builtin_amdgcn_global_load_lds(
            (const __attribute__((address_space(1))) unsigned int*)(const void*)(gA + k0),
            (__attribute__((address_space(3))) unsigned int*)(void*)lA0, 16, 0, 0);
        __builtin_amdgcn_global_load_lds(
            (const __attribute__((address_space(1))) unsigned int*)(const void*)(gA + (size_t)16 * HD + k0),
            (__attribute__((address_space(3))) unsigned int*)(void*)lA1, 16, 0, 0);
        __builtin_amdgcn_global_load_lds(
            (const __attribute__((address_space(1))) unsigned int*)(const void*)(gB + k0),
            (__attribute__((address_space(3))) unsigned int*)(void*)lB0, 16, 0, 0);
        __builtin_amdgcn_global_load_lds(
            (const __attribute__((address_space(1))) unsigned int*)(const void*)(gB + (size_t)16 * HD + k0),
            (__attribute__((address_space(3))) unsigned int*)(void*)lB1, 16, 0, 0);
        __syncthreads();
        short8 af[4], bfr[4];
        #pragma unroll
        for (int i = 0; i < 4; ++i) {
            int ra = wm * 64 + i * 16 + l16;
            af[i] = *(const short8*)&sA[ra * 32 + (quad ^ ((ra >> 1) & 3)) * 8];
        }
        #pragma unroll
        for (int j = 0; j < 4; ++j) {
            int rb = wn * 64 + j * 16 + l16;
            bfr[j] = *(const short8*)&sB[rb * 32 + (quad ^ ((rb >> 1) & 3)) * 8];
        }
        #pragma unroll
        for (int i = 0; i < 4; ++i)
            #pragma unroll
            for (int j = 0; j < 4; ++j)
                acc[i][j] = __builtin_amdgcn_mfma_f32_16x16x32_bf16(af[i], bfr[j], acc[i][j], 0, 0, 0);
        __syncthreads();
    }

    #pragma unroll
    for (int j = 0; j < 4; ++j) {
        int nl = wn * 64 + j * 16 + l16;
        float bb = bv[n0 + nl];
        #pragma unroll
        for (int i = 0; i < 4; ++i) {
            #pragma unroll
            for (int rr = 0; rr < 4; ++rr) {
                int ml = wm * 64 + i * 16 + quad * 4 + rr;
                tileC[ml * 132 + nl] = f2bf(acc[i][j][rr] + bb);
            }
        }
    }
    __syncthreads();
    int r = t >> 1, c0 = (t & 1) * 64;
    int b_ = m0 >> 12, s0 = m0 & 4095;
    #pragma unroll
    for (int v = 0; v < 8; ++v) {
        union { short8 vv; u16 u[8]; } pk;
        #pragma unroll
        for (int e = 0; e < 8; ++e) pk.u[e] = tileC[(c0 + v * 8 + e) * 132 + r];
        *(short8*)&vtb[((size_t)(b_ * HD + n0 + r)) * SEQ + s0 + c0 + v * 8] = pk.vv;
    }
}

// ---------------- Kernel 1 (fallback path only): QKV GEMM 128^2 ----------------
__global__ __launch_bounds__(256, 2) void qkv_gemm(const u16* __restrict__ x,
                                                   const u16* __restrict__ wt,
                                                   const float* __restrict__ bq,
                                                   const float* __restrict__ bk,
                                                   const float* __restrict__ bv,
                                                   u16* __restrict__ qb,
                                                   u16* __restrict__ kbuf,
                                                   u16* __restrict__ vtb) {
    __shared__ __align__(16) u16 sA[128 * 32];
    __shared__ __align__(16) u16 sB[128 * 32];
    __shared__ __align__(16) u16 tileC[128 * 132];
    int z = blockIdx.z;
    const u16* Bt = wt + (size_t)z * HD * HD;
    const float* bias = (z == 0) ? bq : ((z == 1) ? bk : bv);
    int m0 = blockIdx.x * 128, n0 = blockIdx.y * 128;
    int t = threadIdx.x, lane = t & 63, w = t >> 6;
    int quad = lane >> 4, l16 = lane & 15;
    int wm = w >> 1, wn = w & 1;
    floatx4 acc[4][4] = {};

    int srow = w * 32 + (lane >> 2);
    int sswz = (lane & 3) ^ ((lane >> 3) & 3);
    const u16* gA = x + (size_t)(m0 + srow) * HD + sswz * 8;
    const u16* gB = Bt + (size_t)(n0 + srow) * HD + sswz * 8;
    u16* lA0 = &sA[(w * 32) * 32];
    u16* lA1 = &sA[(w * 32 + 16) * 32];
    u16* lB0 = &sB[(w * 32) * 32];
    u16* lB1 = &sB[(w * 32 + 16) * 32];

    for (int k0 = 0; k0 < HD; k0 += 32) {
        __builtin_amdgcn_global_load_lds(
            (const __attribute__((address_space(1))) unsigned int*)(const void*)(gA + k0),
            (__attribute__((address_space(3))) unsigned int*)(void*)lA0, 16, 0, 0);
        __builtin_amdgcn_global_load_lds(
            (const __attribute__((address_space(1))) unsigned int*)(const void*)(gA + (size_t)16 * HD + k0),
            (__attribute__((address_space(3))) unsigned int*)(void*)lA1, 16, 0, 0);
        __builtin_amdgcn_global_load_lds(
            (const __attribute__((address_space(1))) unsigned int*)(const void*)(gB + k0),
            (__attribute__((address_space(3))) unsigned int*)(void*)lB0, 16, 0, 0);
        __builtin_amdgcn_global_load_lds(
            (const __attribute__((address_space(1))) unsigned int*)(const void*)(gB + (size_t)16 * HD + k0),
            (__attribute__((address_space(3))) unsigned int*)(void*)lB1, 16, 0, 0);
        __syncthreads();
        short8 af[4], bfr[4];
        #pragma unroll
        for (int i = 0; i < 4; ++i) {
            int ra = wm * 64 + i * 16 + l16;
            af[i] = *(const short8*)&sA[ra * 32 + (quad ^ ((ra >> 1) & 3)) * 8];
        }
        #pragma unroll
        for (int j = 0; j < 4; ++j) {
            int rb = wn * 64 + j * 16 + l16;
            bfr[j] = *(const short8*)&sB[rb * 32 + (quad ^ ((rb >> 1) & 3)) * 8];
        }
        #pragma unroll
        for (int i = 0; i < 4; ++i)
            #pragma unroll
            for (int j = 0; j < 4; ++j)
                acc[i][j] = __builtin_amdgcn_mfma_f32_16x16x32_bf16(af[i], bfr[j], acc[i][j], 0, 0, 0);
        __syncthreads();
    }

    #pragma unroll
    for (int j = 0; j < 4; ++j) {
        int nl = wn * 64 + j * 16 + l16;
        float bb = bias[n0 + nl];
        #pragma unroll
        for (int i = 0; i < 4; ++i) {
            #pragma unroll
            for (int rr = 0; rr < 4; ++rr) {
                int ml = wm * 64 + i * 16 + quad * 4 + rr;
                tileC[ml * 132 + nl] = f2bf(acc[i][j][rr] + bb);
            }
        }
    }
    __syncthreads();
    int r = t >> 1, c0 = (t & 1) * 64;
    if (z != 2) {
        u16* dst = (z == 0) ? qb : kbuf;
        #pragma unroll
        for (int v = 0; v < 8; ++v) {
            short8 vv = *(const short8*)&tileC[r * 132 + c0 + v * 8];
            *(short8*)&dst[(size_t)(m0 + r) * HD + n0 + c0 + v * 8] = vv;
        }
    } else {
        int b_ = m0 >> 12, s0 = m0 & 4095;
        #pragma unroll
        for (int v = 0; v < 8; ++v) {
            union { short8 vv; u16 u[8]; } pk;
            #pragma unroll
            for (int e = 0; e < 8; ++e) pk.u[e] = tileC[(c0 + v * 8 + e) * 132 + r];
            *(short8*)&vtb[((size_t)(b_ * HD + n0 + r)) * SEQ + s0 + c0 + v * 8] = pk.vv;
        }
    }
}

// ---------------- gemm256: 256x256 tile, counted-vmcnt pipelined GEMM (proven r6) ----------------
template<int LDA, int LDB, int LDC, int KT, int MT, int NT, bool F32OUT>
__global__ __launch_bounds__(512, 2) void gemm256(const u16* __restrict__ A,
                                                  const u16* __restrict__ B,
                                                  void* __restrict__ C,
                                                  float scale) {
    __shared__ __align__(16) u16 ring[4][2][256 * 32];   // 128 KiB
    constexpr int NWG = 4 * MT * NT;
    int wg = xcd_chunk(blockIdx.x, NWG);
    int b = wg / (MT * NT);
    int r = wg % (MT * NT);
    int m0 = (r / NT) * 256, n0 = (r % NT) * 256;
    const u16* Ab = A + (size_t)b * MT * 256 * LDA;
    const u16* Bb = B + (size_t)b * NT * 256 * LDB;

    int t = threadIdx.x, lane = t & 63, w = t >> 6;
    int quad = lane >> 4, l16 = lane & 15;
    int wm = w >> 2, wn = w & 3;

    int srow = w * 32 + (lane >> 2);
    int sswz = (lane & 3) ^ ((lane >> 3) & 3);
    const u16* gAs = Ab + (size_t)(m0 + srow) * LDA + sswz * 8;
    const u16* gBs = Bb + (size_t)(n0 + srow) * LDB + sswz * 8;

    auto stage = [&](int kt_) {
        int s_ = kt_ & 3;
        const u16* a0 = gAs + (size_t)kt_ * 32;
        const u16* b0 = gBs + (size_t)kt_ * 32;
        u16* dA = &ring[s_][0][(w * 32) * 32];
        u16* dB = &ring[s_][1][(w * 32) * 32];
        __builtin_amdgcn_global_load_lds(
            (const __attribute__((address_space(1))) unsigned int*)(const void*)a0,
            (__attribute__((address_space(3))) unsigned int*)(void*)dA, 16, 0, 0);
        __builtin_amdgcn_global_load_lds(
            (const __attribute__((address_space(1))) unsigned int*)(const void*)(a0 + (size_t)16 * LDA),
            (__attribute__((address_space(3))) unsigned int*)(void*)(dA + 16 * 32), 16, 0, 0);
        __builtin_amdgcn_global_load_lds(
            (const __attribute__((address_space(1))) unsigned int*)(const void*)b0,
            (__attribute__((address_space(3))) unsigned int*)(void*)dB, 16, 0, 0);
        __builtin_amdgcn_global_load_lds(
            (const __attribute__((address_space(1))) unsigned int*)(const void*)(b0 + (size_t)16 * LDB),
            (__attribute__((address_space(3))) unsigned int*)(void*)(dB + 16 * 32), 16, 0, 0);
    };

    stage(0); stage(1); stage(2);

    floatx4 acc[8][4] = {};

    for (int kt = 0; kt < KT; ++kt) {
        if (kt + 2 < KT)       asm volatile("s_waitcnt vmcnt(8)" ::: "memory");
        else if (kt + 2 == KT) asm volatile("s_waitcnt vmcnt(4)" ::: "memory");
        else                   asm volatile("s_waitcnt vmcnt(0)" ::: "memory");
        __builtin_amdgcn_s_barrier();
        asm volatile("" ::: "memory");
        if (kt + 3 < KT) stage(kt + 3);

        const u16* As = &ring[kt & 3][0][0];
        const u16* Bs = &ring[kt & 3][1][0];
        short8 bf[4], af[8];
        #pragma unroll
        for (int j = 0; j < 4; ++j) {
            int rb = wn * 64 + j * 16 + l16;
            bf[j] = *(const short8*)&Bs[rb * 32 + (quad ^ ((rb >> 1) & 3)) * 8];
        }
        #pragma unroll
        for (int i = 0; i < 8; ++i) {
            int ra = wm * 128 + i * 16 + l16;
            af[i] = *(const short8*)&As[ra * 32 + (quad ^ ((ra >> 1) & 3)) * 8];
        }
        __builtin_amdgcn_s_setprio(1);
        #pragma unroll
        for (int i = 0; i < 8; ++i)
            #pragma unroll
            for (int j = 0; j < 4; ++j)
                acc[i][j] = __builtin_amdgcn_mfma_f32_16x16x32_bf16(af[i], bf[j], acc[i][j], 0, 0, 0);
        __builtin_amdgcn_s_setprio(0);
    }

    if constexpr (F32OUT) {
        float* Cb = (float*)C + (size_t)b * MT * 256 * LDC;
        #pragma unroll
        for (int i = 0; i < 8; ++i)
            #pragma unroll
            for (int rr = 0; rr < 4; ++rr) {
                int m = m0 + wm * 128 + i * 16 + quad * 4 + rr;
                float* row = Cb + (size_t)m * LDC + n0 + wn * 64 + l16;
                #pragma unroll
                for (int j = 0; j < 4; ++j)
                    row[j * 16] = acc[i][j][rr] * scale;
            }
    } else {
        u16* Cb = (u16*)C + (size_t)b * MT * 256 * LDC;
        #pragma unroll
        for (int i = 0; i < 8; ++i)
            #pragma unroll
            for (int rr = 0; rr < 4; ++rr) {
                int m = m0 + wm * 128 + i * 16 + quad * 4 + rr;
                u16* row = Cb + (size_t)m * LDC + n0 + wn * 64 + l16;
                #pragma unroll
                for (int j = 0; j < 4; ++j)
                    row[j * 16] = f2bf(acc[i][j][rr] * scale);
            }
    }
}

// ---------------- Kernel SM: in-place row softmax on S (bf16) ----------------
__global__ __launch_bounds__(256) void softmax_kernel(u16* __restrict__ S) {
    int w = threadIdx.x >> 6, lane = threadIdx.x & 63;
    size_t row = (size_t)blockIdx.x * 4 + w;
    u16* p = S + row * SEQ;
    float sv[64];
    float mx = -1e30f;
    #pragma unroll
    for (int c = 0; c < 8; ++c) {
        short8 v = *(const short8*)&p[(c * 64 + lane) * 8];
        #pragma unroll
        for (int e = 0; e < 8; ++e) {
            float f = bf2f((u16)v[e]);
            sv[c * 8 + e] = f;
            mx = fmaxf(mx, f);
        }
    }
    mx = fmaxf(mx, __shfl_xor(mx, 1));
    mx = fmaxf(mx, __shfl_xor(mx, 2));
    mx = fmaxf(mx, __shfl_xor(mx, 4));
    mx = fmaxf(mx, __shfl_xor(mx, 8));
    mx = fmaxf(mx, __shfl_xor(mx, 16));
    mx = fmaxf(mx, __shfl_xor(mx, 32));
    float sum = 0.f;
    #pragma unroll
    for (int i = 0; i < 64; ++i) { sv[i] = __expf(sv[i] - mx); sum += sv[i]; }
    sum += __shfl_xor(sum, 1);
    sum += __shfl_xor(sum, 2);
    sum += __shfl_xor(sum, 4);
    sum += __shfl_xor(sum, 8);
    sum += __shfl_xor(sum, 16);
    sum += __shfl_xor(sum, 32);
    float rinv = 1.f / sum;
    #pragma unroll
    for (int c = 0; c < 8; ++c) {
        union { short8 vv; u16 u[8]; } o;
        #pragma unroll
        for (int e = 0; e < 8; ++e) o.u[e] = f2bf(sv[c * 8 + e] * rinv);
        *(short8*)&p[(c * 64 + lane) * 8] = o.vv;
    }
}

// ---------------- Fallback: flash attention (proven, 590us) ----------------
__global__ __launch_bounds__(512, 2) void flash_kernel(const u16* __restrict__ q,
                                                       const u16* __restrict__ k,
                                                       const u16* __restrict__ vt,
                                                       float* __restrict__ out) {
    __shared__ __align__(16) u16 q_lds[64 * 1032];
    __shared__ float Sc[64 * 66];
    __shared__ __align__(16) u16 Pb[64 * 72];
    __shared__ float m_st[64], l_st[64], al_st[64];

    int t = threadIdx.x, lane = t & 63, w = t >> 6;
    int quad = lane >> 4, l16 = lane & 15;
    int j = w & 3, hh = w >> 2;
    int bid = blockIdx.x;
    int xcd = bid & 7;
    int b = xcd >> 1;
    int q0 = (((bid >> 3) << 1) + (xcd & 1)) * 64;

    for (int i = t; i < 64 * 128; i += 512) {
        int r = i >> 7, c8 = (i & 127) * 8;
        *(short8*)&q_lds[r * 1032 + c8] =
            *(const short8*)&q[((size_t)(b * SEQ + q0 + r)) * HD + c8];
    }
    if (t < 64) { m_st[t] = -1e30f; l_st[t] = 0.f; }
    floatx4 o_acc[4][8] = {};
    __syncthreads();

    const u16* kwave = k + ((size_t)(b * SEQ + j * 16 + l16)) * HD + hh * 512 + quad * 8;
    const u16* vwave = vt + ((size_t)(b * HD + w * 128 + l16)) * SEQ + quad * 8;
    int r2 = t >> 3;
    int cg = (t & 7) * 8;

    for (int tt = 0; tt < 64; ++tt) {
        int kb = tt * 64;
        floatx4 s_acc[4] = {};
        const u16* kp = kwave + (size_t)kb * HD;
        #pragma unroll 8
        for (int ks = 0; ks < 16; ++ks) {
            short8 kf = *(const short8*)(kp + ks * 32);
            #pragma unroll
            for (int rb = 0; rb < 4; ++rb) {
                short8 qf = *(const short8*)&q_lds[(rb * 16 + l16) * 1032 + hh * 512 + ks * 32 + quad * 8];
                s_acc[rb] = __builtin_amdgcn_mfma_f32_16x16x32_bf16(qf, kf, s_acc[rb], 0, 0, 0);
            }
        }
        if (hh == 0) {
            #pragma unroll
            for (int rb = 0; rb < 4; ++rb)
                #pragma unroll
                for (int rr = 0; rr < 4; ++rr)
                    Sc[(rb * 16 + quad * 4 + rr) * 66 + j * 16 + l16] = s_acc[rb][rr] * 0.03125f;
        }
        __syncthreads();
        if (hh == 1) {
            #pragma unroll
            for (int rb = 0; rb < 4; ++rb)
                #pragma unroll
                for (int rr = 0; rr < 4; ++rr)
                    Sc[(rb * 16 + quad * 4 + rr) * 66 + j * 16 + l16] += s_acc[rb][rr] * 0.03125f;
        }
        __syncthreads();

        float sv[8];
        float mloc = -1e30f;
        #pragma unroll
        for (int i = 0; i < 8; ++i) { sv[i] = Sc[r2 * 66 + cg + i]; mloc = fmaxf(mloc, sv[i]); }
        mloc = fmaxf(mloc, __shfl_xor(mloc, 1));
        mloc = fmaxf(mloc, __shfl_xor(mloc, 2));
        mloc = fmaxf(mloc, __shfl_xor(mloc, 4));
        float m_old = m_st[r2];
        float m_new = fmaxf(m_old, mloc);
        float alpha = __expf(m_old - m_new);
        float sum = 0.f;
        #pragma unroll
        for (int i = 0; i < 8; ++i) {
            float p = __expf(sv[i] - m_new);
            sum += p;
            Pb[r2 * 72 + cg + i] = f2bf(p);
        }
        sum += __shfl_xor(sum, 1);
        sum += __shfl_xor(sum, 2);
        sum += __shfl_xor(sum, 4);
        if ((t & 7) == 0) {
            m_st[r2] = m_new;
            l_st[r2] = l_st[r2] * alpha + sum;
            al_st[r2] = alpha;
        }
        __syncthreads();

        #pragma unroll
        for (int rb = 0; rb < 4; ++rb) {
            float a0 = al_st[rb * 16 + quad * 4 + 0];
            float a1 = al_st[rb * 16 + quad * 4 + 1];
            float a2 = al_st[rb * 16 + quad * 4 + 2];
            float a3 = al_st[rb * 16 + quad * 4 + 3];
            #pragma unroll
            for (int dt = 0; dt < 8; ++dt) {
                o_acc[rb][dt][0] *= a0;
                o_acc[rb][dt][1] *= a1;
                o_acc[rb][dt][2] *= a2;
                o_acc[rb][dt][3] *= a3;
            }
        }
        short8 pf[4][2];
        #pragma unroll
        for (int rb = 0; rb < 4; ++rb)
            #pragma unroll
            for (int ks2 = 0; ks2 < 2; ++ks2)
                pf[rb][ks2] = *(const short8*)&Pb[(rb * 16 + l16) * 72 + ks2 * 32 + quad * 8];
        const u16* vp = vwave + kb;
        #pragma unroll
        for (int dt = 0; dt < 8; ++dt) {
            short8 vf0 = *(const short8*)(vp + (size_t)dt * 16 * SEQ);
            short8 vf1 = *(const short8*)(vp + (size_t)dt * 16 * SEQ + 32);
            #pragma unroll
            for (int rb = 0; rb < 4; ++rb) {
                o_acc[rb][dt] = __builtin_amdgcn_mfma_f32_16x16x32_bf16(pf[rb][0], vf0, o_acc[rb][dt], 0, 0, 0);
                o_acc[rb][dt] = __builtin_amdgcn_mfma_f32_16x16x32_bf16(pf[rb][1], vf1, o_acc[rb][dt], 0, 0, 0);
            }
        }
    }

    #pragma unroll
    for (int rb = 0; rb < 4; ++rb) {
        #pragma unroll
        for (int rr = 0; rr < 4; ++rr) {
            int row = rb * 16 + quad * 4 + rr;
            float linv = 1.f / l_st[row];
            #pragma unroll
            for (int dt = 0; dt < 8; ++dt) {
                out[((size_t)(b * SEQ + q0 + row)) * HD + w * 128 + dt * 16 + l16] =
                    o_acc[rb][dt][rr] * linv;
            }
        }
    }
}

extern "C" void kernel_launch(void* const* d_in, const int* in_sizes, int n_in,
                              void* d_out, int out_size, void* d_ws, size_t ws_size,
                              hipStream_t stream) {
    const float* x  = (const float*)d_in[0];
    const float* Wq = (const float*)d_in[1];
    const float* bq = (const float*)d_in[2];
    const float* Wk = (const float*)d_in[3];
    const float* bk = (const float*)d_in[4];
    const float* Wv = (const float*)d_in[5];
    const float* bv = (const float*)d_in[6];
    float* out = (float*)d_out;
    char* ws = (char*)d_ws;
    const size_t MB = 1024 * 1024;

    if (ws_size >= 224 * MB) {
        // Unfused path. Layout (peak 224 MB):
        //   vtb @0 (32MB) | qb @32 (32MB) | kb @64 (32MB) | S @96..224 (128MB)
        //   xb @96 (32MB, dead before S written) | wt @128 (6MB, dead too)
        u16* vtb = (u16*)ws;
        u16* qb  = (u16*)(ws + 32 * MB);
        u16* kb  = (u16*)(ws + 64 * MB);
        u16* S   = (u16*)(ws + 96 * MB);
        u16* xb  = (u16*)(ws + 96 * MB);
        u16* wt  = (u16*)(ws + 128 * MB);

        cvt_kernel<<<dim3(4096), 256, 0, stream>>>(x, xb, (4 * SEQ * HD) / 4);
        wt_kernel<<<dim3(16, 16, 3), 256, 0, stream>>>(Wq, Wk, Wv, wt);
        // Q,K: counted-vmcnt 256^2 structure; V: validated 128^2 with transpose bounce
        qkv256<<<dim3(512), 512, 0, stream>>>(xb, wt, bq, bk, qb, kb);
        v_gemm<<<dim3(128, 8), 256, 0, stream>>>(xb, wt + (size_t)2 * HD * HD, bv, vtb);
        // S = Q K^T / 32 : M=N=4096, K=1024 per batch, bf16 out
        gemm256<HD, HD, SEQ, 32, 16, 16, false><<<dim3(1024), 512, 0, stream>>>(qb, kb, S, 0.03125f);
        softmax_kernel<<<dim3(4096), 256, 0, stream>>>(S);
        // O = P V : M=4096, N=1024, K=4096 per batch, f32 out (B = vt rows over d)
        gemm256<SEQ, SEQ, HD, 128, 16, 4, true><<<dim3(256), 512, 0, stream>>>(S, vtb, out, 1.0f);
    } else {
        // Fallback: proven flash path (134 MB).
        u16* xb  = (u16*)ws;
        u16* wt  = (u16*)(ws + 32 * MB);
        u16* qb  = (u16*)(ws + 38 * MB);
        u16* kb  = (u16*)(ws + 70 * MB);
        u16* vtb = (u16*)(ws + 102 * MB);

        cvt_kernel<<<dim3(4096), 256, 0, stream>>>(x, xb, (4 * SEQ * HD) / 4);
        wt_kernel<<<dim3(16, 16, 3), 256, 0, stream>>>(Wq, Wk, Wv, wt);
        qkv_gemm<<<dim3(128, 8, 3), 256, 0, stream>>>(xb, wt, bq, bk, bv, qb, kb, vtb);
        flash_kernel<<<dim3(256), 512, 0, stream>>>(qb, kb, vtb, out);
    }
}

// Round 9
// 504.914 us; speedup vs baseline: 1.3396x; 1.0862x over previous
//
#include <hip/hip_runtime.h>

typedef unsigned short u16;
typedef __attribute__((ext_vector_type(8))) short short8;
typedef __attribute__((ext_vector_type(4))) short short4v;
typedef __attribute__((ext_vector_type(4))) float floatx4;

#define HD 1024
#define SEQ 4096

__device__ inline u16 f2bf(float f) {
    union { float f; unsigned int i; } c; c.f = f;
    unsigned int r = c.i + 0x7fffu + ((c.i >> 16) & 1u);
    return (u16)(r >> 16);
}

__device__ inline float bf2f(u16 h) {
    union { unsigned int u; float f; } c; c.u = ((unsigned int)h) << 16;
    return c.f;
}

// bijective XCD-chunk swizzle (m204): nwg % 8 == 0 required.
__device__ inline int xcd_chunk(int bid, int nwg) {
    int q = nwg >> 3;
    return (bid & 7) * q + (bid >> 3);
}

__device__ inline void glds16(const u16* g, u16* l) {
    __builtin_amdgcn_global_load_lds(
        (const __attribute__((address_space(1))) unsigned int*)(const void*)g,
        (__attribute__((address_space(3))) unsigned int*)(void*)l, 16, 0, 0);
}

// ---------------- Kernel A: x f32 -> bf16 ----------------
__global__ __launch_bounds__(256) void cvt_kernel(const float* __restrict__ in,
                                                  u16* __restrict__ out, int n4) {
    int idx = blockIdx.x * 256 + threadIdx.x;
    int stride = gridDim.x * 256;
    for (int i = idx; i < n4; i += stride) {
        floatx4 v = ((const floatx4*)in)[i];
        short4v o;
        o[0] = (short)f2bf(v[0]); o[1] = (short)f2bf(v[1]);
        o[2] = (short)f2bf(v[2]); o[3] = (short)f2bf(v[3]);
        ((short4v*)out)[i] = o;
    }
}

// ---------------- Kernel 0: W f32 [k][n] -> Wt bf16 [n][k], 3 matrices ----------------
__global__ __launch_bounds__(256) void wt_kernel(const float* __restrict__ Wq,
                                                 const float* __restrict__ Wk,
                                                 const float* __restrict__ Wv,
                                                 u16* __restrict__ wt) {
    __shared__ u16 tile[64 * 65];
    int z = blockIdx.z;
    const float* W = (z == 0) ? Wq : ((z == 1) ? Wk : Wv);
    u16* out = wt + (size_t)z * HD * HD;
    int k0 = blockIdx.x * 64, n0 = blockIdx.y * 64;
    int t = threadIdx.x;
    int r = t >> 4, c4 = (t & 15) * 4;
    for (int h = 0; h < 4; ++h) {
        int row = r + h * 16;
        floatx4 v = *(const floatx4*)(W + (size_t)(k0 + row) * HD + n0 + c4);
        tile[row * 65 + c4 + 0] = f2bf(v[0]);
        tile[row * 65 + c4 + 1] = f2bf(v[1]);
        tile[row * 65 + c4 + 2] = f2bf(v[2]);
        tile[row * 65 + c4 + 3] = f2bf(v[3]);
    }
    __syncthreads();
    int r2 = t >> 3, c8 = (t & 7) * 8;
    union { short8 v; u16 u[8]; } buf;
    for (int h = 0; h < 2; ++h) {
        int rr = r2 + h * 32;
        #pragma unroll
        for (int i = 0; i < 8; ++i) buf.u[i] = tile[(c8 + i) * 65 + rr];
        *(short8*)(out + (size_t)(n0 + rr) * HD + k0 + c8) = buf.v;
    }
}

// ======================================================================
// BK=64 pipelined 256^2 GEMM core (r9 — r8 with the publish race FIXED):
//  - 2-slot LDS ring [2][2][256*64] = 128 KiB
//  - per iter (PROVEN r6/r7 ordering): vmcnt(0) [own tile-kt loads done,
//    issued one full compute phase earlier so the drain is ~free]
//    -> s_barrier [ALL waves' tile-kt loads published; also retires all
//    compute(kt-1) reads of the slot stage(kt+1) will overwrite]
//    -> stage(kt+1) [8 loads fly during compute]
//    -> 8-phase compute: phase p issues ds_reads for p+1's fragments, then
//    a setprio-wrapped 8-MFMA cluster (intra-wave LDS||MFMA overlap)
//  - r8's bug: barrier BEFORE vmcnt -> compute read other waves' unlanded
//    LDS (vmcnt is per-wave; the barrier-after-vmcnt is what publishes).
//  - BK=64 both-sides swizzle: LDS[row][s] = G[row][s ^ (row&7)]
//    (8 lanes/16B-granule per b128 -> minimal 8 bank-cycles, conflict-free)
// ======================================================================
#define RD_A(i, ks) (*(const short8*)&As[(wm * 128 + (i) * 16 + l16) * 64 + ((((ks) * 4 + quad)) ^ (l16 & 7)) * 8])
#define RD_B(j, ks) (*(const short8*)&Bs[(wn * 64 + (j) * 16 + l16) * 64 + ((((ks) * 4 + quad)) ^ (l16 & 7)) * 8])

#define GEMM256_CORE(KTN, LDA_, LDB_)                                                   \
    int t = threadIdx.x, lane = t & 63, w = t >> 6;                                     \
    int quad = lane >> 4, l16 = lane & 15;                                              \
    int wm = w >> 2, wn = w & 3;                                                        \
    int l8r = lane >> 3;                                                                \
    int sswz = (lane & 7) ^ l8r;                                                        \
    const u16* gAs = Ab + (size_t)(m0 + w * 32 + l8r) * LDA_ + sswz * 8;                \
    const u16* gBs = Bb + (size_t)(n0 + w * 32 + l8r) * LDB_ + sswz * 8;                \
    auto stage = [&](int kt_) {                                                         \
        int s_ = kt_ & 1;                                                               \
        const u16* a0 = gAs + (size_t)kt_ * 64;                                         \
        const u16* b0 = gBs + (size_t)kt_ * 64;                                         \
        _Pragma("unroll")                                                               \
        for (int L = 0; L < 4; ++L) {                                                   \
            glds16(a0 + (size_t)(8 * L) * LDA_, &ring[s_][0][(w * 32 + 8 * L) * 64]);   \
            glds16(b0 + (size_t)(8 * L) * LDB_, &ring[s_][1][(w * 32 + 8 * L) * 64]);   \
        }                                                                               \
    };                                                                                  \
    floatx4 acc[8][4] = {};                                                             \
    stage(0);                                                                           \
    for (int kt = 0; kt < (KTN); ++kt) {                                                \
        asm volatile("s_waitcnt vmcnt(0)" ::: "memory");  /* own tile-kt landed */      \
        __builtin_amdgcn_s_barrier();                     /* publish to all waves */    \
        asm volatile("" ::: "memory");                                                  \
        if (kt + 1 < (KTN)) stage(kt + 1);  /* slot read at kt-1, retired pre-bar */    \
        const u16* As = &ring[kt & 1][0][0];                                            \
        const u16* Bs = &ring[kt & 1][1][0];                                            \
        short8 bfr[2][4];                                                               \
        short8 afr[2][2];                                                               \
        _Pragma("unroll")                                                               \
        for (int j = 0; j < 4; ++j) bfr[0][j] = RD_B(j, 0);                             \
        afr[0][0] = RD_A(0, 0);                                                         \
        afr[0][1] = RD_A(1, 0);                                                         \
        _Pragma("unroll")                                                               \
        for (int p = 0; p < 8; ++p) {                                                   \
            int ks = p >> 2, q = p & 3;                                                 \
            int cur = p & 1, nxt = cur ^ 1;                                             \
            if (p < 7) {                                                                \
                int pn = p + 1;                                                         \
                int ksn = pn >> 2, qn = pn & 3;                                         \
                if (qn == 0) {                                                          \
                    _Pragma("unroll")                                                   \
                    for (int j = 0; j < 4; ++j) bfr[1][j] = RD_B(j, 1);                 \
                }                                                                       \
                afr[nxt][0] = RD_A(2 * qn, ksn);                                        \
                afr[nxt][1] = RD_A(2 * qn + 1, ksn);                                    \
            }                                                                           \
            __builtin_amdgcn_s_setprio(1);                                              \
            _Pragma("unroll")                                                           \
            for (int j = 0; j < 4; ++j) {                                               \
                acc[2 * q][j] = __builtin_amdgcn_mfma_f32_16x16x32_bf16(afr[cur][0], bfr[ks][j], acc[2 * q][j], 0, 0, 0);       \
                acc[2 * q + 1][j] = __builtin_amdgcn_mfma_f32_16x16x32_bf16(afr[cur][1], bfr[ks][j], acc[2 * q + 1][j], 0, 0, 0); \
            }                                                                           \
            __builtin_amdgcn_s_setprio(0);                                              \
        }                                                                               \
    }

// ---------------- gemm256: C[b] = scale * A[b] B[b]^T ----------------
template<int LDA, int LDB, int LDC, int KT, int MT, int NT, bool F32OUT>
__global__ __launch_bounds__(512, 2) void gemm256(const u16* __restrict__ A,
                                                  const u16* __restrict__ B,
                                                  void* __restrict__ C,
                                                  float scale) {
    __shared__ __align__(16) u16 ring[2][2][256 * 64];   // 128 KiB
    constexpr int NWG = 4 * MT * NT;
    int wg = xcd_chunk(blockIdx.x, NWG);
    int b = wg / (MT * NT);
    int r = wg % (MT * NT);
    int m0 = (r / NT) * 256, n0 = (r % NT) * 256;
    const u16* Ab = A + (size_t)b * MT * 256 * LDA;
    const u16* Bb = B + (size_t)b * NT * 256 * LDB;

    GEMM256_CORE(KT, LDA, LDB)

    if constexpr (F32OUT) {
        float* Cb = (float*)C + (size_t)b * MT * 256 * LDC;
        #pragma unroll
        for (int i = 0; i < 8; ++i)
            #pragma unroll
            for (int rr = 0; rr < 4; ++rr) {
                int m = m0 + wm * 128 + i * 16 + quad * 4 + rr;
                float* row = Cb + (size_t)m * LDC + n0 + wn * 64 + l16;
                #pragma unroll
                for (int j = 0; j < 4; ++j)
                    row[j * 16] = acc[i][j][rr] * scale;
            }
    } else {
        u16* Cb = (u16*)C + (size_t)b * MT * 256 * LDC;
        #pragma unroll
        for (int i = 0; i < 8; ++i)
            #pragma unroll
            for (int rr = 0; rr < 4; ++rr) {
                int m = m0 + wm * 128 + i * 16 + quad * 4 + rr;
                u16* row = Cb + (size_t)m * LDC + n0 + wn * 64 + l16;
                #pragma unroll
                for (int j = 0; j < 4; ++j)
                    row[j * 16] = f2bf(acc[i][j][rr] * scale);
            }
    }
}

// ---------------- qkv256: Q,K projections (same core, bias fused) ----------------
__global__ __launch_bounds__(512, 2) void qkv256(const u16* __restrict__ x,
                                                 const u16* __restrict__ wt,
                                                 const float* __restrict__ bq,
                                                 const float* __restrict__ bk,
                                                 u16* __restrict__ qb,
                                                 u16* __restrict__ kbuf) {
    __shared__ __align__(16) u16 ring[2][2][256 * 64];   // 128 KiB
    int wg = xcd_chunk(blockIdx.x, 512);
    int z = wg >> 8;
    int r = wg & 255;
    int m0 = (r >> 2) * 256, n0 = (r & 3) * 256;
    const u16* Ab = x;
    const u16* Bb = wt + (size_t)z * HD * HD;
    const float* bias = z ? bk : bq;
    u16* C = z ? kbuf : qb;

    GEMM256_CORE(16, HD, HD)

    float bb[4];
    #pragma unroll
    for (int j = 0; j < 4; ++j) bb[j] = bias[n0 + wn * 64 + j * 16 + l16];
    #pragma unroll
    for (int i = 0; i < 8; ++i)
        #pragma unroll
        for (int rr = 0; rr < 4; ++rr) {
            int m = m0 + wm * 128 + i * 16 + quad * 4 + rr;
            u16* row = C + (size_t)m * HD + n0 + wn * 64 + l16;
            #pragma unroll
            for (int j = 0; j < 4; ++j)
                row[j * 16] = f2bf(acc[i][j][rr] + bb[j]);
        }
}

// ---------------- v_gemm: V projection (validated 128^2, transpose bounce) ----------------
__global__ __launch_bounds__(256, 2) void v_gemm(const u16* __restrict__ x,
                                                 const u16* __restrict__ wtv,
                                                 const float* __restrict__ bv,
                                                 u16* __restrict__ vtb) {
    __shared__ __align__(16) u16 sA[128 * 32];
    __shared__ __align__(16) u16 sB[128 * 32];
    __shared__ __align__(16) u16 tileC[128 * 132];
    int m0 = blockIdx.x * 128, n0 = blockIdx.y * 128;
    int t = threadIdx.x, lane = t & 63, w = t >> 6;
    int quad = lane >> 4, l16 = lane & 15;
    int wm = w >> 1, wn = w & 1;
    floatx4 acc[4][4] = {};

    int srow = w * 32 + (lane >> 2);
    int sswz = (lane & 3) ^ ((lane >> 3) & 3);
    const u16* gA = x + (size_t)(m0 + srow) * HD + sswz * 8;
    const u16* gB = wtv + (size_t)(n0 + srow) * HD + sswz * 8;
    u16* lA0 = &sA[(w * 32) * 32];
    u16* lA1 = &sA[(w * 32 + 16) * 32];
    u16* lB0 = &sB[(w * 32) * 32];
    u16* lB1 = &sB[(w * 32 + 16) * 32];

    for (int k0 = 0; k0 < HD; k0 += 32) {
        glds16(gA + k0, lA0);
        glds16(gA + (size_t)16 * HD + k0, lA1);
        glds16(gB + k0, lB0);
        glds16(gB + (size_t)16 * HD + k0, lB1);
        __syncthreads();
        short8 af[4], bfr[4];
        #pragma unroll
        for (int i = 0; i < 4; ++i) {
            int ra = wm * 64 + i * 16 + l16;
            af[i] = *(const short8*)&sA[ra * 32 + (quad ^ ((ra >> 1) & 3)) * 8];
        }
        #pragma unroll
        for (int j = 0; j < 4; ++j) {
            int rb = wn * 64 + j * 16 + l16;
            bfr[j] = *(const short8*)&sB[rb * 32 + (quad ^ ((rb >> 1) & 3)) * 8];
        }
        #pragma unroll
        for (int i = 0; i < 4; ++i)
            #pragma unroll
            for (int j = 0; j < 4; ++j)
                acc[i][j] = __builtin_amdgcn_mfma_f32_16x16x32_bf16(af[i], bfr[j], acc[i][j], 0, 0, 0);
        __syncthreads();
    }

    #pragma unroll
    for (int j = 0; j < 4; ++j) {
        int nl = wn * 64 + j * 16 + l16;
        float bb = bv[n0 + nl];
        #pragma unroll
        for (int i = 0; i < 4; ++i) {
            #pragma unroll
            for (int rr = 0; rr < 4; ++rr) {
                int ml = wm * 64 + i * 16 + quad * 4 + rr;
                tileC[ml * 132 + nl] = f2bf(acc[i][j][rr] + bb);
            }
        }
    }
    __syncthreads();
    int r = t >> 1, c0 = (t & 1) * 64;
    int b_ = m0 >> 12, s0 = m0 & 4095;
    #pragma unroll
    for (int v = 0; v < 8; ++v) {
        union { short8 vv; u16 u[8]; } pk;
        #pragma unroll
        for (int e = 0; e < 8; ++e) pk.u[e] = tileC[(c0 + v * 8 + e) * 132 + r];
        *(short8*)&vtb[((size_t)(b_ * HD + n0 + r)) * SEQ + s0 + c0 + v * 8] = pk.vv;
    }
}

// ---------------- Kernel 1 (fallback path only): QKV GEMM 128^2 ----------------
__global__ __launch_bounds__(256, 2) void qkv_gemm(const u16* __restrict__ x,
                                                   const u16* __restrict__ wt,
                                                   const float* __restrict__ bq,
                                                   const float* __restrict__ bk,
                                                   const float* __restrict__ bv,
                                                   u16* __restrict__ qb,
                                                   u16* __restrict__ kbuf,
                                                   u16* __restrict__ vtb) {
    __shared__ __align__(16) u16 sA[128 * 32];
    __shared__ __align__(16) u16 sB[128 * 32];
    __shared__ __align__(16) u16 tileC[128 * 132];
    int z = blockIdx.z;
    const u16* Bt = wt + (size_t)z * HD * HD;
    const float* bias = (z == 0) ? bq : ((z == 1) ? bk : bv);
    int m0 = blockIdx.x * 128, n0 = blockIdx.y * 128;
    int t = threadIdx.x, lane = t & 63, w = t >> 6;
    int quad = lane >> 4, l16 = lane & 15;
    int wm = w >> 1, wn = w & 1;
    floatx4 acc[4][4] = {};

    int srow = w * 32 + (lane >> 2);
    int sswz = (lane & 3) ^ ((lane >> 3) & 3);
    const u16* gA = x + (size_t)(m0 + srow) * HD + sswz * 8;
    const u16* gB = Bt + (size_t)(n0 + srow) * HD + sswz * 8;
    u16* lA0 = &sA[(w * 32) * 32];
    u16* lA1 = &sA[(w * 32 + 16) * 32];
    u16* lB0 = &sB[(w * 32) * 32];
    u16* lB1 = &sB[(w * 32 + 16) * 32];

    for (int k0 = 0; k0 < HD; k0 += 32) {
        glds16(gA + k0, lA0);
        glds16(gA + (size_t)16 * HD + k0, lA1);
        glds16(gB + k0, lB0);
        glds16(gB + (size_t)16 * HD + k0, lB1);
        __syncthreads();
        short8 af[4], bfr[4];
        #pragma unroll
        for (int i = 0; i < 4; ++i) {
            int ra = wm * 64 + i * 16 + l16;
            af[i] = *(const short8*)&sA[ra * 32 + (quad ^ ((ra >> 1) & 3)) * 8];
        }
        #pragma unroll
        for (int j = 0; j < 4; ++j) {
            int rb = wn * 64 + j * 16 + l16;
            bfr[j] = *(const short8*)&sB[rb * 32 + (quad ^ ((rb >> 1) & 3)) * 8];
        }
        #pragma unroll
        for (int i = 0; i < 4; ++i)
            #pragma unroll
            for (int j = 0; j < 4; ++j)
                acc[i][j] = __builtin_amdgcn_mfma_f32_16x16x32_bf16(af[i], bfr[j], acc[i][j], 0, 0, 0);
        __syncthreads();
    }

    #pragma unroll
    for (int j = 0; j < 4; ++j) {
        int nl = wn * 64 + j * 16 + l16;
        float bb = bias[n0 + nl];
        #pragma unroll
        for (int i = 0; i < 4; ++i) {
            #pragma unroll
            for (int rr = 0; rr < 4; ++rr) {
                int ml = wm * 64 + i * 16 + quad * 4 + rr;
                tileC[ml * 132 + nl] = f2bf(acc[i][j][rr] + bb);
            }
        }
    }
    __syncthreads();
    int r = t >> 1, c0 = (t & 1) * 64;
    if (z != 2) {
        u16* dst = (z == 0) ? qb : kbuf;
        #pragma unroll
        for (int v = 0; v < 8; ++v) {
            short8 vv = *(const short8*)&tileC[r * 132 + c0 + v * 8];
            *(short8*)&dst[(size_t)(m0 + r) * HD + n0 + c0 + v * 8] = vv;
        }
    } else {
        int b_ = m0 >> 12, s0 = m0 & 4095;
        #pragma unroll
        for (int v = 0; v < 8; ++v) {
            union { short8 vv; u16 u[8]; } pk;
            #pragma unroll
            for (int e = 0; e < 8; ++e) pk.u[e] = tileC[(c0 + v * 8 + e) * 132 + r];
            *(short8*)&vtb[((size_t)(b_ * HD + n0 + r)) * SEQ + s0 + c0 + v * 8] = pk.vv;
        }
    }
}

// ---------------- Kernel SM: in-place row softmax on S (bf16) ----------------
__global__ __launch_bounds__(256) void softmax_kernel(u16* __restrict__ S) {
    int w = threadIdx.x >> 6, lane = threadIdx.x & 63;
    size_t row = (size_t)blockIdx.x * 4 + w;
    u16* p = S + row * SEQ;
    float sv[64];
    float mx = -1e30f;
    #pragma unroll
    for (int c = 0; c < 8; ++c) {
        short8 v = *(const short8*)&p[(c * 64 + lane) * 8];
        #pragma unroll
        for (int e = 0; e < 8; ++e) {
            float f = bf2f((u16)v[e]);
            sv[c * 8 + e] = f;
            mx = fmaxf(mx, f);
        }
    }
    mx = fmaxf(mx, __shfl_xor(mx, 1));
    mx = fmaxf(mx, __shfl_xor(mx, 2));
    mx = fmaxf(mx, __shfl_xor(mx, 4));
    mx = fmaxf(mx, __shfl_xor(mx, 8));
    mx = fmaxf(mx, __shfl_xor(mx, 16));
    mx = fmaxf(mx, __shfl_xor(mx, 32));
    float sum = 0.f;
    #pragma unroll
    for (int i = 0; i < 64; ++i) { sv[i] = __expf(sv[i] - mx); sum += sv[i]; }
    sum += __shfl_xor(sum, 1);
    sum += __shfl_xor(sum, 2);
    sum += __shfl_xor(sum, 4);
    sum += __shfl_xor(sum, 8);
    sum += __shfl_xor(sum, 16);
    sum += __shfl_xor(sum, 32);
    float rinv = 1.f / sum;
    #pragma unroll
    for (int c = 0; c < 8; ++c) {
        union { short8 vv; u16 u[8]; } o;
        #pragma unroll
        for (int e = 0; e < 8; ++e) o.u[e] = f2bf(sv[c * 8 + e] * rinv);
        *(short8*)&p[(c * 64 + lane) * 8] = o.vv;
    }
}

// ---------------- Fallback: flash attention (proven, 590us) ----------------
__global__ __launch_bounds__(512, 2) void flash_kernel(const u16* __restrict__ q,
                                                       const u16* __restrict__ k,
                                                       const u16* __restrict__ vt,
                                                       float* __restrict__ out) {
    __shared__ __align__(16) u16 q_lds[64 * 1032];
    __shared__ float Sc[64 * 66];
    __shared__ __align__(16) u16 Pb[64 * 72];
    __shared__ float m_st[64], l_st[64], al_st[64];

    int t = threadIdx.x, lane = t & 63, w = t >> 6;
    int quad = lane >> 4, l16 = lane & 15;
    int j = w & 3, hh = w >> 2;
    int bid = blockIdx.x;
    int xcd = bid & 7;
    int b = xcd >> 1;
    int q0 = (((bid >> 3) << 1) + (xcd & 1)) * 64;

    for (int i = t; i < 64 * 128; i += 512) {
        int r = i >> 7, c8 = (i & 127) * 8;
        *(short8*)&q_lds[r * 1032 + c8] =
            *(const short8*)&q[((size_t)(b * SEQ + q0 + r)) * HD + c8];
    }
    if (t < 64) { m_st[t] = -1e30f; l_st[t] = 0.f; }
    floatx4 o_acc[4][8] = {};
    __syncthreads();

    const u16* kwave = k + ((size_t)(b * SEQ + j * 16 + l16)) * HD + hh * 512 + quad * 8;
    const u16* vwave = vt + ((size_t)(b * HD + w * 128 + l16)) * SEQ + quad * 8;
    int r2 = t >> 3;
    int cg = (t & 7) * 8;

    for (int tt = 0; tt < 64; ++tt) {
        int kb = tt * 64;
        floatx4 s_acc[4] = {};
        const u16* kp = kwave + (size_t)kb * HD;
        #pragma unroll 8
        for (int ks = 0; ks < 16; ++ks) {
            short8 kf = *(const short8*)(kp + ks * 32);
            #pragma unroll
            for (int rb = 0; rb < 4; ++rb) {
                short8 qf = *(const short8*)&q_lds[(rb * 16 + l16) * 1032 + hh * 512 + ks * 32 + quad * 8];
                s_acc[rb] = __builtin_amdgcn_mfma_f32_16x16x32_bf16(qf, kf, s_acc[rb], 0, 0, 0);
            }
        }
        if (hh == 0) {
            #pragma unroll
            for (int rb = 0; rb < 4; ++rb)
                #pragma unroll
                for (int rr = 0; rr < 4; ++rr)
                    Sc[(rb * 16 + quad * 4 + rr) * 66 + j * 16 + l16] = s_acc[rb][rr] * 0.03125f;
        }
        __syncthreads();
        if (hh == 1) {
            #pragma unroll
            for (int rb = 0; rb < 4; ++rb)
                #pragma unroll
                for (int rr = 0; rr < 4; ++rr)
                    Sc[(rb * 16 + quad * 4 + rr) * 66 + j * 16 + l16] += s_acc[rb][rr] * 0.03125f;
        }
        __syncthreads();

        float sv[8];
        float mloc = -1e30f;
        #pragma unroll
        for (int i = 0; i < 8; ++i) { sv[i] = Sc[r2 * 66 + cg + i]; mloc = fmaxf(mloc, sv[i]); }
        mloc = fmaxf(mloc, __shfl_xor(mloc, 1));
        mloc = fmaxf(mloc, __shfl_xor(mloc, 2));
        mloc = fmaxf(mloc, __shfl_xor(mloc, 4));
        float m_old = m_st[r2];
        float m_new = fmaxf(m_old, mloc);
        float alpha = __expf(m_old - m_new);
        float sum = 0.f;
        #pragma unroll
        for (int i = 0; i < 8; ++i) {
            float p = __expf(sv[i] - m_new);
            sum += p;
            Pb[r2 * 72 + cg + i] = f2bf(p);
        }
        sum += __shfl_xor(sum, 1);
        sum += __shfl_xor(sum, 2);
        sum += __shfl_xor(sum, 4);
        if ((t & 7) == 0) {
            m_st[r2] = m_new;
            l_st[r2] = l_st[r2] * alpha + sum;
            al_st[r2] = alpha;
        }
        __syncthreads();

        #pragma unroll
        for (int rb = 0; rb < 4; ++rb) {
            float a0 = al_st[rb * 16 + quad * 4 + 0];
            float a1 = al_st[rb * 16 + quad * 4 + 1];
            float a2 = al_st[rb * 16 + quad * 4 + 2];
            float a3 = al_st[rb * 16 + quad * 4 + 3];
            #pragma unroll
            for (int dt = 0; dt < 8; ++dt) {
                o_acc[rb][dt][0] *= a0;
                o_acc[rb][dt][1] *= a1;
                o_acc[rb][dt][2] *= a2;
                o_acc[rb][dt][3] *= a3;
            }
        }
        short8 pf[4][2];
        #pragma unroll
        for (int rb = 0; rb < 4; ++rb)
            #pragma unroll
            for (int ks2 = 0; ks2 < 2; ++ks2)
                pf[rb][ks2] = *(const short8*)&Pb[(rb * 16 + l16) * 72 + ks2 * 32 + quad * 8];
        const u16* vp = vwave + kb;
        #pragma unroll
        for (int dt = 0; dt < 8; ++dt) {
            short8 vf0 = *(const short8*)(vp + (size_t)dt * 16 * SEQ);
            short8 vf1 = *(const short8*)(vp + (size_t)dt * 16 * SEQ + 32);
            #pragma unroll
            for (int rb = 0; rb < 4; ++rb) {
                o_acc[rb][dt] = __builtin_amdgcn_mfma_f32_16x16x32_bf16(pf[rb][0], vf0, o_acc[rb][dt], 0, 0, 0);
                o_acc[rb][dt] = __builtin_amdgcn_mfma_f32_16x16x32_bf16(pf[rb][1], vf1, o_acc[rb][dt], 0, 0, 0);
            }
        }
    }

    #pragma unroll
    for (int rb = 0; rb < 4; ++rb) {
        #pragma unroll
        for (int rr = 0; rr < 4; ++rr) {
            int row = rb * 16 + quad * 4 + rr;
            float linv = 1.f / l_st[row];
            #pragma unroll
            for (int dt = 0; dt < 8; ++dt) {
                out[((size_t)(b * SEQ + q0 + row)) * HD + w * 128 + dt * 16 + l16] =
                    o_acc[rb][dt][rr] * linv;
            }
        }
    }
}

extern "C" void kernel_launch(void* const* d_in, const int* in_sizes, int n_in,
                              void* d_out, int out_size, void* d_ws, size_t ws_size,
                              hipStream_t stream) {
    const float* x  = (const float*)d_in[0];
    const float* Wq = (const float*)d_in[1];
    const float* bq = (const float*)d_in[2];
    const float* Wk = (const float*)d_in[3];
    const float* bk = (const float*)d_in[4];
    const float* Wv = (const float*)d_in[5];
    const float* bv = (const float*)d_in[6];
    float* out = (float*)d_out;
    char* ws = (char*)d_ws;
    const size_t MB = 1024 * 1024;

    if (ws_size >= 224 * MB) {
        // Unfused path. Layout (peak 224 MB):
        //   vtb @0 (32MB) | qb @32 (32MB) | kb @64 (32MB) | S @96..224 (128MB)
        //   xb @96 (32MB, dead before S written) | wt @128 (6MB, dead too)
        u16* vtb = (u16*)ws;
        u16* qb  = (u16*)(ws + 32 * MB);
        u16* kb  = (u16*)(ws + 64 * MB);
        u16* S   = (u16*)(ws + 96 * MB);
        u16* xb  = (u16*)(ws + 96 * MB);
        u16* wt  = (u16*)(ws + 128 * MB);

        cvt_kernel<<<dim3(4096), 256, 0, stream>>>(x, xb, (4 * SEQ * HD) / 4);
        wt_kernel<<<dim3(16, 16, 3), 256, 0, stream>>>(Wq, Wk, Wv, wt);
        qkv256<<<dim3(512), 512, 0, stream>>>(xb, wt, bq, bk, qb, kb);
        v_gemm<<<dim3(128, 8), 256, 0, stream>>>(xb, wt + (size_t)2 * HD * HD, bv, vtb);
        // S = Q K^T / 32 : M=N=4096, K=1024 (KT=16 x BK=64) per batch, bf16 out
        gemm256<HD, HD, SEQ, 16, 16, 16, false><<<dim3(1024), 512, 0, stream>>>(qb, kb, S, 0.03125f);
        softmax_kernel<<<dim3(4096), 256, 0, stream>>>(S);
        // O = P V : M=4096, N=1024, K=4096 (KT=64) per batch, f32 out
        gemm256<SEQ, SEQ, HD, 64, 16, 4, true><<<dim3(256), 512, 0, stream>>>(S, vtb, out, 1.0f);
    } else {
        // Fallback: proven flash path (134 MB).
        u16* xb  = (u16*)ws;
        u16* wt  = (u16*)(ws + 32 * MB);
        u16* qb  = (u16*)(ws + 38 * MB);
        u16* kb  = (u16*)(ws + 70 * MB);
        u16* vtb = (u16*)(ws + 102 * MB);

        cvt_kernel<<<dim3(4096), 256, 0, stream>>>(x, xb, (4 * SEQ * HD) / 4);
        wt_kernel<<<dim3(16, 16, 3), 256, 0, stream>>>(Wq, Wk, Wv, wt);
        qkv_gemm<<<dim3(128, 8, 3), 256, 0, stream>>>(xb, wt, bq, bk, bv, qb, kb, vtb);
        flash_kernel<<<dim3(256), 512, 0, stream>>>(qb, kb, vtb, out);
    }
}